// Round 1
// baseline (2373.932 us; speedup 1.0000x reference)
//
#include <hip/hip_runtime.h>
#include <cstddef>

#define S_LEN 2048
#define DMODEL 2048
#define NH 16
#define NKV 4
#define HD 128
#define BATCH 2
#define MROWS (BATCH * S_LEN) /* 4096 */

// ---------------------------------------------------------------------------
// Generic fp32 GEMM: C[M,N] = A[M,K] @ B[K,N], all row-major.
// 64x64 block tile, K-slab 16, 256 threads, 4x4 accumulator per thread.
// As stored transposed [k][m] with pad 68 (conflict-free), Bs [k][n] unpadded.
// ---------------------------------------------------------------------------
__global__ __launch_bounds__(256) void gemm_f32(
    const float* __restrict__ A, const float* __restrict__ Bm,
    float* __restrict__ C, int M, int N, int K)
{
  __shared__ float As[16][68];
  __shared__ float Bs[16][64];
  const int tid = threadIdx.x;
  const int tx = tid & 15, ty = tid >> 4;
  const int m0 = blockIdx.y * 64, n0 = blockIdx.x * 64;
  // A loader: row = tid/4 (0..63), col group = (tid%4)*4
  const int lam = tid >> 2;
  const int lak = (tid & 3) << 2;
  // B loader: row = tid/16 (0..15), col group = (tid%16)*4
  const int lbk = tid >> 4;
  const int lbn = (tid & 15) << 2;
  const float* Aptr = A + (size_t)(m0 + lam) * K + lak;
  const float* Bptr = Bm + (size_t)lbk * N + n0 + lbn;

  float acc[4][4] = {};

  for (int k0 = 0; k0 < K; k0 += 16) {
    const float4 av = *(const float4*)(Aptr + k0);
    const float4 bv = *(const float4*)(Bptr + (size_t)k0 * N);
    As[lak + 0][lam] = av.x;
    As[lak + 1][lam] = av.y;
    As[lak + 2][lam] = av.z;
    As[lak + 3][lam] = av.w;
    *(float4*)&Bs[lbk][lbn] = bv;
    __syncthreads();
#pragma unroll
    for (int kk = 0; kk < 16; ++kk) {
      const float4 a4 = *(const float4*)&As[kk][ty << 2];
      const float4 b4 = *(const float4*)&Bs[kk][tx << 2];
      const float ar[4] = {a4.x, a4.y, a4.z, a4.w};
      const float br[4] = {b4.x, b4.y, b4.z, b4.w};
#pragma unroll
      for (int i = 0; i < 4; ++i)
#pragma unroll
        for (int j = 0; j < 4; ++j)
          acc[i][j] = fmaf(ar[i], br[j], acc[i][j]);
    }
    __syncthreads();
  }

#pragma unroll
  for (int i = 0; i < 4; ++i) {
    float4 cv;
    cv.x = acc[i][0]; cv.y = acc[i][1]; cv.z = acc[i][2]; cv.w = acc[i][3];
    *(float4*)&C[(size_t)(m0 + (ty << 2) + i) * N + n0 + (tx << 2)] = cv;
  }
}

// ---------------------------------------------------------------------------
// Flash-style causal attention, fp32, RoPE fused into Q/K LDS staging.
// Block = (q-tile of 32 rows, head h, batch b). 256 threads (tx 0..15, ty 0..15).
// Thread owns score rows r=2*ty+{0,1}, cols c = tx+16*{0..3};
// O accumulator rows r=2*ty+{0,1}, d = 8*tx+{0..7}.
// LDS: Qs[32][132] + KV[64*132] (K then V, reused) + Ps[32][68] = 59,392 B.
// qin may alias aout (each block reads exactly the region it later writes).
// ---------------------------------------------------------------------------
__global__ __launch_bounds__(256) void attn_fwd(
    const float* qin, const float* __restrict__ kin, const float* __restrict__ vin,
    const float* __restrict__ cosp, const float* __restrict__ sinp,
    float* aout)
{
  __shared__ float Qs[32][132];
  __shared__ float KV[64 * 132];
  __shared__ float Ps[32][68];

  const int tid = threadIdx.x;
  const int tx = tid & 15, ty = tid >> 4;
  const int qt = blockIdx.x, h = blockIdx.y, b = blockIdx.z;
  const int q0 = qt * 32;
  const int kvh = h >> 2; // N_REP = 4
  const float scale = 0.08838834764831845f; // 1/sqrt(128)

  // ---- stage Q tile with RoPE + scale ----
#pragma unroll
  for (int it = 0; it < 4; ++it) {
    const int idx = it * 256 + tid;
    const int r = idx >> 5, g = idx & 31;
    const int srow = q0 + r;
    const float4 x = *(const float4*)&qin[(size_t)(b * S_LEN + srow) * DMODEL + h * HD + 4 * g];
    const int i0 = 2 * g, i1 = 2 * g + 1;
    const float c0 = cosp[srow * 64 + i0], s0 = sinp[srow * 64 + i0];
    const float c1 = cosp[srow * 64 + i1], s1 = sinp[srow * 64 + i1];
    Qs[r][i0]      = (x.x * c0 - x.y * s0) * scale;
    Qs[r][i1]      = (x.z * c1 - x.w * s1) * scale;
    Qs[r][64 + i0] = (x.y * c0 + x.x * s0) * scale;
    Qs[r][64 + i1] = (x.w * c1 + x.z * s1) * scale;
  }

  float m_run[2] = {-1e30f, -1e30f};
  float l_run[2] = {0.f, 0.f};
  float o[2][8] = {};

  const int nkt = (q0 + 31) / 64 + 1; // causal: only tiles with k0 <= q0+31

  for (int kt = 0; kt < nkt; ++kt) {
    const int k0 = kt * 64;
    __syncthreads(); // previous-iter KV/Ps reads done; also covers Qs staging (iter 0)

    // ---- stage K tile with RoPE: KV[c*132 + d] ----
#pragma unroll
    for (int it = 0; it < 8; ++it) {
      const int idx = it * 256 + tid;
      const int c = idx >> 5, g = idx & 31;
      const int srow = k0 + c;
      const float4 x = *(const float4*)&kin[(size_t)(b * S_LEN + srow) * (NKV * HD) + kvh * HD + 4 * g];
      const int i0 = 2 * g, i1 = 2 * g + 1;
      const float c0 = cosp[srow * 64 + i0], s0 = sinp[srow * 64 + i0];
      const float c1 = cosp[srow * 64 + i1], s1 = sinp[srow * 64 + i1];
      KV[c * 132 + i0]      = x.x * c0 - x.y * s0;
      KV[c * 132 + i1]      = x.z * c1 - x.w * s1;
      KV[c * 132 + 64 + i0] = x.y * c0 + x.x * s0;
      KV[c * 132 + 64 + i1] = x.w * c1 + x.z * s1;
    }
    __syncthreads();

    // ---- scores: sc[j][i] = (Q[2ty+j] . K[tx+16i]) (Q pre-scaled) ----
    float sc[2][4] = {{0.f, 0.f, 0.f, 0.f}, {0.f, 0.f, 0.f, 0.f}};
    for (int d = 0; d < HD; d += 4) {
      const float4 qa = *(const float4*)&Qs[2 * ty + 0][d];
      const float4 qb = *(const float4*)&Qs[2 * ty + 1][d];
#pragma unroll
      for (int i = 0; i < 4; ++i) {
        const float4 kv4 = *(const float4*)&KV[(tx + 16 * i) * 132 + d];
        sc[0][i] += qa.x * kv4.x + qa.y * kv4.y + qa.z * kv4.z + qa.w * kv4.w;
        sc[1][i] += qb.x * kv4.x + qb.y * kv4.y + qb.z * kv4.z + qb.w * kv4.w;
      }
    }

    // ---- causal mask + online softmax update ----
#pragma unroll
    for (int j = 0; j < 2; ++j) {
      const int qpos = q0 + 2 * ty + j;
      float rm = -1e30f;
#pragma unroll
      for (int i = 0; i < 4; ++i) {
        const int kpos = k0 + tx + 16 * i;
        sc[j][i] = (kpos <= qpos) ? sc[j][i] : -1e30f;
        rm = fmaxf(rm, sc[j][i]);
      }
#pragma unroll
      for (int msk = 1; msk < 16; msk <<= 1)
        rm = fmaxf(rm, __shfl_xor(rm, msk));
      const float mnew = fmaxf(m_run[j], rm);
      const float alpha = __expf(m_run[j] - mnew);
      float rs = 0.f;
      float pv[4];
#pragma unroll
      for (int i = 0; i < 4; ++i) {
        pv[i] = __expf(sc[j][i] - mnew);
        rs += pv[i];
      }
#pragma unroll
      for (int msk = 1; msk < 16; msk <<= 1)
        rs += __shfl_xor(rs, msk);
      l_run[j] = l_run[j] * alpha + rs;
      m_run[j] = mnew;
#pragma unroll
      for (int i = 0; i < 8; ++i) o[j][i] *= alpha;
#pragma unroll
      for (int i = 0; i < 4; ++i) Ps[2 * ty + j][tx + 16 * i] = pv[i];
    }
    __syncthreads(); // scores done reading K; Ps visible -> overwrite KV with V

    // ---- stage V tile: KV[c*132 + d] ----
#pragma unroll
    for (int it = 0; it < 8; ++it) {
      const int idx = it * 256 + tid;
      const int c = idx >> 5, g = idx & 31;
      *(float4*)&KV[c * 132 + 4 * g] =
          *(const float4*)&vin[(size_t)(b * S_LEN + k0 + c) * (NKV * HD) + kvh * HD + 4 * g];
    }
    __syncthreads();

    // ---- PV accumulate ----
    for (int c = 0; c < 64; ++c) {
      const float p0 = Ps[2 * ty + 0][c];
      const float p1 = Ps[2 * ty + 1][c];
      const float4 va = *(const float4*)&KV[c * 132 + (tx << 3)];
      const float4 vb = *(const float4*)&KV[c * 132 + (tx << 3) + 4];
      const float vr[8] = {va.x, va.y, va.z, va.w, vb.x, vb.y, vb.z, vb.w};
#pragma unroll
      for (int i = 0; i < 8; ++i) {
        o[0][i] = fmaf(p0, vr[i], o[0][i]);
        o[1][i] = fmaf(p1, vr[i], o[1][i]);
      }
    }
  }

  // ---- epilogue: normalize and store ----
#pragma unroll
  for (int j = 0; j < 2; ++j) {
    const float inv = 1.0f / l_run[j];
    const int row = b * S_LEN + q0 + 2 * ty + j;
    float4 r0, r1;
    r0.x = o[j][0] * inv; r0.y = o[j][1] * inv; r0.z = o[j][2] * inv; r0.w = o[j][3] * inv;
    r1.x = o[j][4] * inv; r1.y = o[j][5] * inv; r1.z = o[j][6] * inv; r1.w = o[j][7] * inv;
    float* dst = &aout[(size_t)row * DMODEL + h * HD + (tx << 3)];
    *(float4*)dst = r0;
    *(float4*)(dst + 4) = r1;
  }
}

// ---------------------------------------------------------------------------
extern "C" void kernel_launch(void* const* d_in, const int* in_sizes, int n_in,
                              void* d_out, int out_size, void* d_ws, size_t ws_size,
                              hipStream_t stream) {
  const float* hs   = (const float*)d_in[0];
  // d_in[1] attention_mask: exactly causal tril(0 / -1e9) -> handled analytically
  const float* cosp = (const float*)d_in[2];
  const float* sinp = (const float*)d_in[3];
  const float* Wq   = (const float*)d_in[4];
  const float* Wk   = (const float*)d_in[5];
  const float* Wv   = (const float*)d_in[6];
  const float* Wo   = (const float*)d_in[7];
  float* out = (float*)d_out;

  // workspace: q (33.5MB) | k (8.4MB) | v (8.4MB); attn output aliases q.
  float* q    = (float*)d_ws;
  float* kbuf = q + (size_t)MROWS * DMODEL;
  float* vbuf = kbuf + (size_t)MROWS * (NKV * HD);
  float* ao   = q; // safe alias: block reads its q region before writing it

  dim3 blk(256);
  gemm_f32<<<dim3(DMODEL / 64, MROWS / 64), blk, 0, stream>>>(hs, Wq, q,    MROWS, DMODEL,   DMODEL);
  gemm_f32<<<dim3((NKV * HD) / 64, MROWS / 64), blk, 0, stream>>>(hs, Wk, kbuf, MROWS, NKV * HD, DMODEL);
  gemm_f32<<<dim3((NKV * HD) / 64, MROWS / 64), blk, 0, stream>>>(hs, Wv, vbuf, MROWS, NKV * HD, DMODEL);
  attn_fwd<<<dim3(S_LEN / 32, NH, BATCH), blk, 0, stream>>>(q, kbuf, vbuf, cosp, sinp, ao);
  gemm_f32<<<dim3(DMODEL / 64, MROWS / 64), blk, 0, stream>>>(ao, Wo, out, MROWS, DMODEL, DMODEL);
}

// Round 2
// 1669.799 us; speedup vs baseline: 1.4217x; 1.4217x over previous
//
#include <hip/hip_runtime.h>
#include <cstddef>

#define S_LEN 2048
#define DMODEL 2048
#define NH 16
#define NKV 4
#define HD 128
#define BATCH 2
#define MROWS (BATCH * S_LEN) /* 4096 */

typedef __attribute__((ext_vector_type(8))) short bf16x8;
typedef __attribute__((ext_vector_type(4))) float floatx4;

__device__ inline short f2bf(float f) {
  union { float f; unsigned u; } v; v.f = f;
  unsigned r = v.u + 0x7FFFu + ((v.u >> 16) & 1u); // RNE
  return (short)(r >> 16);
}

// ---------------------------------------------------------------------------
// bf16 MFMA GEMM: C[M,N] = A[M,K] @ B[K,N]; A,B fp32 in global, cast to bf16
// during LDS staging; fp32 accumulate. 128x128 tile, BK=32, 256 thr (4 waves),
// wave = 64x64 quadrant = 4x4 grid of v_mfma_f32_16x16x32_bf16.
// LDS rows padded to 56 shorts (112 B): 16B-aligned b128 frag reads,
// stride/16=7 odd -> 16 rows spread over 8 superbanks (2-way, free).
// A-frag: lane holds A[m=lane&15][k=quad*8+j]; B-frag: B^T[n=lane&15][k=...];
// C/D: col=lane&15, row=quad*4+reg  (verified layouts, m89/m91).
// ---------------------------------------------------------------------------
__global__ __launch_bounds__(256) void gemm_bf16(
    const float* __restrict__ A, const float* __restrict__ Bm,
    float* __restrict__ C, int M, int N, int K)
{
  __shared__ short As[128][56];
  __shared__ short Bs[128][56];

  const int tid  = threadIdx.x;
  const int wave = tid >> 6;
  const int lane = tid & 63;
  const int l16  = lane & 15;
  const int quad = lane >> 4;
  const int wm   = (wave & 1) * 64;
  const int wn   = (wave >> 1) * 64;
  const int m0   = blockIdx.y * 128;
  const int n0   = blockIdx.x * 128;

  // A stage: thread -> row am = tid>>1, k-half akh = (tid&1)*16
  const int am  = tid >> 1;
  const int akh = (tid & 1) << 4;
  const float* Ap = A + (size_t)(m0 + am) * K + akh;

  // B stage: thread -> col bn = tid>>1, k-half bkh = (tid&1)*16
  const int bn  = tid >> 1;
  const int bkh = (tid & 1) << 4;
  const float* Bp = Bm + n0 + bn;

  floatx4 acc[4][4];
#pragma unroll
  for (int i = 0; i < 4; ++i)
#pragma unroll
    for (int j = 0; j < 4; ++j)
#pragma unroll
      for (int r = 0; r < 4; ++r) acc[i][j][r] = 0.f;

  for (int k0 = 0; k0 < K; k0 += 32) {
    // global loads into registers (before barrier, overlaps prior compute)
    const float4 a0 = *(const float4*)(Ap + k0 + 0);
    const float4 a1 = *(const float4*)(Ap + k0 + 4);
    const float4 a2 = *(const float4*)(Ap + k0 + 8);
    const float4 a3 = *(const float4*)(Ap + k0 + 12);
    float bv[16];
#pragma unroll
    for (int kk = 0; kk < 16; ++kk)
      bv[kk] = Bp[(size_t)(k0 + bkh + kk) * N];

    __syncthreads(); // prior iter frag reads complete before overwrite

    short* ad = &As[am][akh];
    ad[0]  = f2bf(a0.x); ad[1]  = f2bf(a0.y); ad[2]  = f2bf(a0.z); ad[3]  = f2bf(a0.w);
    ad[4]  = f2bf(a1.x); ad[5]  = f2bf(a1.y); ad[6]  = f2bf(a1.z); ad[7]  = f2bf(a1.w);
    ad[8]  = f2bf(a2.x); ad[9]  = f2bf(a2.y); ad[10] = f2bf(a2.z); ad[11] = f2bf(a2.w);
    ad[12] = f2bf(a3.x); ad[13] = f2bf(a3.y); ad[14] = f2bf(a3.z); ad[15] = f2bf(a3.w);
    short* bd = &Bs[bn][bkh];
#pragma unroll
    for (int kk = 0; kk < 16; ++kk) bd[kk] = f2bf(bv[kk]);

    __syncthreads();

    bf16x8 af[4], bf[4];
#pragma unroll
    for (int i = 0; i < 4; ++i)
      af[i] = *(const bf16x8*)&As[wm + i * 16 + l16][quad << 3];
#pragma unroll
    for (int j = 0; j < 4; ++j)
      bf[j] = *(const bf16x8*)&Bs[wn + j * 16 + l16][quad << 3];
#pragma unroll
    for (int i = 0; i < 4; ++i)
#pragma unroll
      for (int j = 0; j < 4; ++j)
        acc[i][j] = __builtin_amdgcn_mfma_f32_16x16x32_bf16(af[i], bf[j], acc[i][j], 0, 0, 0);
  }

  // epilogue: C[m0+wm+i*16+quad*4+r][n0+wn+j*16+l16]
#pragma unroll
  for (int i = 0; i < 4; ++i)
#pragma unroll
    for (int r = 0; r < 4; ++r) {
      const int row = m0 + wm + i * 16 + (quad << 2) + r;
      float* crow = &C[(size_t)row * N + n0 + wn + l16];
#pragma unroll
      for (int j = 0; j < 4; ++j)
        crow[j * 16] = acc[i][j][r];
    }
}

// ---------------------------------------------------------------------------
// Flash-style causal attention, fp32, RoPE fused into Q/K LDS staging.
// (unchanged from round 1 — MFMA conversion planned next round)
// ---------------------------------------------------------------------------
__global__ __launch_bounds__(256) void attn_fwd(
    const float* qin, const float* __restrict__ kin, const float* __restrict__ vin,
    const float* __restrict__ cosp, const float* __restrict__ sinp,
    float* aout)
{
  __shared__ float Qs[32][132];
  __shared__ float KV[64 * 132];
  __shared__ float Ps[32][68];

  const int tid = threadIdx.x;
  const int tx = tid & 15, ty = tid >> 4;
  const int qt = blockIdx.x, h = blockIdx.y, b = blockIdx.z;
  const int q0 = qt * 32;
  const int kvh = h >> 2;
  const float scale = 0.08838834764831845f;

#pragma unroll
  for (int it = 0; it < 4; ++it) {
    const int idx = it * 256 + tid;
    const int r = idx >> 5, g = idx & 31;
    const int srow = q0 + r;
    const float4 x = *(const float4*)&qin[(size_t)(b * S_LEN + srow) * DMODEL + h * HD + 4 * g];
    const int i0 = 2 * g, i1 = 2 * g + 1;
    const float c0 = cosp[srow * 64 + i0], s0 = sinp[srow * 64 + i0];
    const float c1 = cosp[srow * 64 + i1], s1 = sinp[srow * 64 + i1];
    Qs[r][i0]      = (x.x * c0 - x.y * s0) * scale;
    Qs[r][i1]      = (x.z * c1 - x.w * s1) * scale;
    Qs[r][64 + i0] = (x.y * c0 + x.x * s0) * scale;
    Qs[r][64 + i1] = (x.w * c1 + x.z * s1) * scale;
  }

  float m_run[2] = {-1e30f, -1e30f};
  float l_run[2] = {0.f, 0.f};
  float o[2][8] = {};

  const int nkt = (q0 + 31) / 64 + 1;

  for (int kt = 0; kt < nkt; ++kt) {
    const int k0 = kt * 64;
    __syncthreads();

#pragma unroll
    for (int it = 0; it < 8; ++it) {
      const int idx = it * 256 + tid;
      const int c = idx >> 5, g = idx & 31;
      const int srow = k0 + c;
      const float4 x = *(const float4*)&kin[(size_t)(b * S_LEN + srow) * (NKV * HD) + kvh * HD + 4 * g];
      const int i0 = 2 * g, i1 = 2 * g + 1;
      const float c0 = cosp[srow * 64 + i0], s0 = sinp[srow * 64 + i0];
      const float c1 = cosp[srow * 64 + i1], s1 = sinp[srow * 64 + i1];
      KV[c * 132 + i0]      = x.x * c0 - x.y * s0;
      KV[c * 132 + i1]      = x.z * c1 - x.w * s1;
      KV[c * 132 + 64 + i0] = x.y * c0 + x.x * s0;
      KV[c * 132 + 64 + i1] = x.w * c1 + x.z * s1;
    }
    __syncthreads();

    float sc[2][4] = {{0.f, 0.f, 0.f, 0.f}, {0.f, 0.f, 0.f, 0.f}};
    for (int d = 0; d < HD; d += 4) {
      const float4 qa = *(const float4*)&Qs[2 * ty + 0][d];
      const float4 qb = *(const float4*)&Qs[2 * ty + 1][d];
#pragma unroll
      for (int i = 0; i < 4; ++i) {
        const float4 kv4 = *(const float4*)&KV[(tx + 16 * i) * 132 + d];
        sc[0][i] += qa.x * kv4.x + qa.y * kv4.y + qa.z * kv4.z + qa.w * kv4.w;
        sc[1][i] += qb.x * kv4.x + qb.y * kv4.y + qb.z * kv4.z + qb.w * kv4.w;
      }
    }

#pragma unroll
    for (int j = 0; j < 2; ++j) {
      const int qpos = q0 + 2 * ty + j;
      float rm = -1e30f;
#pragma unroll
      for (int i = 0; i < 4; ++i) {
        const int kpos = k0 + tx + 16 * i;
        sc[j][i] = (kpos <= qpos) ? sc[j][i] : -1e30f;
        rm = fmaxf(rm, sc[j][i]);
      }
#pragma unroll
      for (int msk = 1; msk < 16; msk <<= 1)
        rm = fmaxf(rm, __shfl_xor(rm, msk));
      const float mnew = fmaxf(m_run[j], rm);
      const float alpha = __expf(m_run[j] - mnew);
      float rs = 0.f;
      float pv[4];
#pragma unroll
      for (int i = 0; i < 4; ++i) {
        pv[i] = __expf(sc[j][i] - mnew);
        rs += pv[i];
      }
#pragma unroll
      for (int msk = 1; msk < 16; msk <<= 1)
        rs += __shfl_xor(rs, msk);
      l_run[j] = l_run[j] * alpha + rs;
      m_run[j] = mnew;
#pragma unroll
      for (int i = 0; i < 8; ++i) o[j][i] *= alpha;
#pragma unroll
      for (int i = 0; i < 4; ++i) Ps[2 * ty + j][tx + 16 * i] = pv[i];
    }
    __syncthreads();

#pragma unroll
    for (int it = 0; it < 8; ++it) {
      const int idx = it * 256 + tid;
      const int c = idx >> 5, g = idx & 31;
      *(float4*)&KV[c * 132 + 4 * g] =
          *(const float4*)&vin[(size_t)(b * S_LEN + k0 + c) * (NKV * HD) + kvh * HD + 4 * g];
    }
    __syncthreads();

    for (int c = 0; c < 64; ++c) {
      const float p0 = Ps[2 * ty + 0][c];
      const float p1 = Ps[2 * ty + 1][c];
      const float4 va = *(const float4*)&KV[c * 132 + (tx << 3)];
      const float4 vb = *(const float4*)&KV[c * 132 + (tx << 3) + 4];
      const float vr[8] = {va.x, va.y, va.z, va.w, vb.x, vb.y, vb.z, vb.w};
#pragma unroll
      for (int i = 0; i < 8; ++i) {
        o[0][i] = fmaf(p0, vr[i], o[0][i]);
        o[1][i] = fmaf(p1, vr[i], o[1][i]);
      }
    }
  }

#pragma unroll
  for (int j = 0; j < 2; ++j) {
    const float inv = 1.0f / l_run[j];
    const int row = b * S_LEN + q0 + 2 * ty + j;
    float4 r0, r1;
    r0.x = o[j][0] * inv; r0.y = o[j][1] * inv; r0.z = o[j][2] * inv; r0.w = o[j][3] * inv;
    r1.x = o[j][4] * inv; r1.y = o[j][5] * inv; r1.z = o[j][6] * inv; r1.w = o[j][7] * inv;
    float* dst = &aout[(size_t)row * DMODEL + h * HD + (tx << 3)];
    *(float4*)dst = r0;
    *(float4*)(dst + 4) = r1;
  }
}

// ---------------------------------------------------------------------------
extern "C" void kernel_launch(void* const* d_in, const int* in_sizes, int n_in,
                              void* d_out, int out_size, void* d_ws, size_t ws_size,
                              hipStream_t stream) {
  const float* hs   = (const float*)d_in[0];
  const float* cosp = (const float*)d_in[2];
  const float* sinp = (const float*)d_in[3];
  const float* Wq   = (const float*)d_in[4];
  const float* Wk   = (const float*)d_in[5];
  const float* Wv   = (const float*)d_in[6];
  const float* Wo   = (const float*)d_in[7];
  float* out = (float*)d_out;

  float* q    = (float*)d_ws;
  float* kbuf = q + (size_t)MROWS * DMODEL;
  float* vbuf = kbuf + (size_t)MROWS * (NKV * HD);
  float* ao   = q; // safe alias: attn block reads its q region before writing it

  dim3 blk(256);
  gemm_bf16<<<dim3(DMODEL / 128, MROWS / 128), blk, 0, stream>>>(hs, Wq, q,    MROWS, DMODEL,   DMODEL);
  gemm_bf16<<<dim3((NKV * HD) / 128, MROWS / 128), blk, 0, stream>>>(hs, Wk, kbuf, MROWS, NKV * HD, DMODEL);
  gemm_bf16<<<dim3((NKV * HD) / 128, MROWS / 128), blk, 0, stream>>>(hs, Wv, vbuf, MROWS, NKV * HD, DMODEL);
  attn_fwd<<<dim3(S_LEN / 32, NH, BATCH), blk, 0, stream>>>(q, kbuf, vbuf, cosp, sinp, ao);
  gemm_bf16<<<dim3(DMODEL / 128, MROWS / 128), blk, 0, stream>>>(ao, Wo, out, MROWS, DMODEL, DMODEL);
}

// Round 4
// 736.681 us; speedup vs baseline: 3.2225x; 2.2667x over previous
//
#include <hip/hip_runtime.h>
#include <cstddef>

#define S_LEN 2048
#define DMODEL 2048
#define NH 16
#define NKV 4
#define HD 128
#define BATCH 2
#define MROWS (BATCH * S_LEN) /* 4096 */
#define KVD (NKV * HD)        /* 512 */

typedef __attribute__((ext_vector_type(8))) short bf16x8;
typedef __attribute__((ext_vector_type(4))) float floatx4;
typedef __attribute__((ext_vector_type(8))) _Float16 half8;
typedef __attribute__((ext_vector_type(4))) _Float16 half4;
typedef __attribute__((ext_vector_type(2))) _Float16 half2v;

#define QSCALE 0.1275310255f /* log2(e)/sqrt(128): folds softmax scale + exp2 conversion */

__device__ inline short f2bf(float f) {
  union { float f; unsigned u; } v; v.f = f;
  unsigned r = v.u + 0x7FFFu + ((v.u >> 16) & 1u); // RNE
  return (short)(r >> 16);
}

__device__ inline half2v pack2h(float lo, float hi) {
  union { decltype(__builtin_amdgcn_cvt_pkrtz(0.f, 0.f)) raw; half2v h; } u;
  u.raw = __builtin_amdgcn_cvt_pkrtz(lo, hi);
  return u.h;
}

// ---------------------------------------------------------------------------
// bf16 MFMA GEMM (unchanged from round 2, verified): C[M,N] = A[M,K] @ B[K,N]
// ---------------------------------------------------------------------------
__global__ __launch_bounds__(256) void gemm_bf16(
    const float* __restrict__ A, const float* __restrict__ Bm,
    float* __restrict__ C, int M, int N, int K)
{
  __shared__ short As[128][56];
  __shared__ short Bs[128][56];

  const int tid  = threadIdx.x;
  const int wave = tid >> 6;
  const int lane = tid & 63;
  const int l16  = lane & 15;
  const int quad = lane >> 4;
  const int wm   = (wave & 1) * 64;
  const int wn   = (wave >> 1) * 64;
  const int m0   = blockIdx.y * 128;
  const int n0   = blockIdx.x * 128;

  const int am  = tid >> 1;
  const int akh = (tid & 1) << 4;
  const float* Ap = A + (size_t)(m0 + am) * K + akh;

  const int bn  = tid >> 1;
  const int bkh = (tid & 1) << 4;
  const float* Bp = Bm + n0 + bn;

  floatx4 acc[4][4];
#pragma unroll
  for (int i = 0; i < 4; ++i)
#pragma unroll
    for (int j = 0; j < 4; ++j)
#pragma unroll
      for (int r = 0; r < 4; ++r) acc[i][j][r] = 0.f;

  for (int k0 = 0; k0 < K; k0 += 32) {
    const float4 a0 = *(const float4*)(Ap + k0 + 0);
    const float4 a1 = *(const float4*)(Ap + k0 + 4);
    const float4 a2 = *(const float4*)(Ap + k0 + 8);
    const float4 a3 = *(const float4*)(Ap + k0 + 12);
    float bv[16];
#pragma unroll
    for (int kk = 0; kk < 16; ++kk)
      bv[kk] = Bp[(size_t)(k0 + bkh + kk) * N];

    __syncthreads();

    short* ad = &As[am][akh];
    ad[0]  = f2bf(a0.x); ad[1]  = f2bf(a0.y); ad[2]  = f2bf(a0.z); ad[3]  = f2bf(a0.w);
    ad[4]  = f2bf(a1.x); ad[5]  = f2bf(a1.y); ad[6]  = f2bf(a1.z); ad[7]  = f2bf(a1.w);
    ad[8]  = f2bf(a2.x); ad[9]  = f2bf(a2.y); ad[10] = f2bf(a2.z); ad[11] = f2bf(a2.w);
    ad[12] = f2bf(a3.x); ad[13] = f2bf(a3.y); ad[14] = f2bf(a3.z); ad[15] = f2bf(a3.w);
    short* bd = &Bs[bn][bkh];
#pragma unroll
    for (int kk = 0; kk < 16; ++kk) bd[kk] = f2bf(bv[kk]);

    __syncthreads();

    bf16x8 af[4], bf[4];
#pragma unroll
    for (int i = 0; i < 4; ++i)
      af[i] = *(const bf16x8*)&As[wm + i * 16 + l16][quad << 3];
#pragma unroll
    for (int j = 0; j < 4; ++j)
      bf[j] = *(const bf16x8*)&Bs[wn + j * 16 + l16][quad << 3];
#pragma unroll
    for (int i = 0; i < 4; ++i)
#pragma unroll
      for (int j = 0; j < 4; ++j)
        acc[i][j] = __builtin_amdgcn_mfma_f32_16x16x32_bf16(af[i], bf[j], acc[i][j], 0, 0, 0);
  }

#pragma unroll
  for (int i = 0; i < 4; ++i)
#pragma unroll
    for (int r = 0; r < 4; ++r) {
      const int row = m0 + wm + i * 16 + (quad << 2) + r;
      float* crow = &C[(size_t)row * N + n0 + wn + l16];
#pragma unroll
      for (int j = 0; j < 4; ++j)
        crow[j * 16] = acc[i][j][r];
    }
}

// ---------------------------------------------------------------------------
// qprep: fp32 Q -> f16, RoPE applied, pre-scaled by log2e/sqrt(HD).
// One block per row (b*S+s), 256 threads = 16 heads x 16 pair-groups.
// ---------------------------------------------------------------------------
__global__ __launch_bounds__(256) void qprep(
    const float* __restrict__ q, const float* __restrict__ cosp,
    const float* __restrict__ sinp, _Float16* __restrict__ Qr)
{
  const int row = blockIdx.x;
  const int sl = row & (S_LEN - 1);
  const int h = threadIdx.x >> 4, g = threadIdx.x & 15;
  const float* src = q + (size_t)row * DMODEL + h * HD + 8 * g;
  const float4 xa = *(const float4*)src;
  const float4 xb = *(const float4*)(src + 4);
  const float4 c4 = *(const float4*)&cosp[sl * 64 + 4 * g];
  const float4 s4 = *(const float4*)&sinp[sl * 64 + 4 * g];
  const float p1[4] = {xa.x, xa.z, xb.x, xb.z};
  const float p2[4] = {xa.y, xa.w, xb.y, xb.w};
  const float cc[4] = {c4.x, c4.y, c4.z, c4.w};
  const float ss[4] = {s4.x, s4.y, s4.z, s4.w};
  half4 o1, o2;
#pragma unroll
  for (int u = 0; u < 4; ++u) {
    o1[u] = (_Float16)((p1[u] * cc[u] - p2[u] * ss[u]) * QSCALE);
    o2[u] = (_Float16)((p2[u] * cc[u] + p1[u] * ss[u]) * QSCALE);
  }
  _Float16* dst = Qr + (size_t)row * DMODEL + h * HD + 4 * g;
  *(half4*)dst = o1;
  *(half4*)(dst + 64) = o2;
}

// ---------------------------------------------------------------------------
// kprep: fp32 K -> f16, RoPE applied (no scale). 4 rows per block.
// ---------------------------------------------------------------------------
__global__ __launch_bounds__(256) void kprep(
    const float* __restrict__ k, const float* __restrict__ cosp,
    const float* __restrict__ sinp, _Float16* __restrict__ Kr)
{
  const int row = blockIdx.x * 4 + (threadIdx.x >> 6);
  const int sl = row & (S_LEN - 1);
  const int t = threadIdx.x & 63;
  const int h = t >> 4, g = t & 15;
  const float* src = k + (size_t)row * KVD + h * HD + 8 * g;
  const float4 xa = *(const float4*)src;
  const float4 xb = *(const float4*)(src + 4);
  const float4 c4 = *(const float4*)&cosp[sl * 64 + 4 * g];
  const float4 s4 = *(const float4*)&sinp[sl * 64 + 4 * g];
  const float p1[4] = {xa.x, xa.z, xb.x, xb.z};
  const float p2[4] = {xa.y, xa.w, xb.y, xb.w};
  const float cc[4] = {c4.x, c4.y, c4.z, c4.w};
  const float ss[4] = {s4.x, s4.y, s4.z, s4.w};
  half4 o1, o2;
#pragma unroll
  for (int u = 0; u < 4; ++u) {
    o1[u] = (_Float16)(p1[u] * cc[u] - p2[u] * ss[u]);
    o2[u] = (_Float16)(p2[u] * cc[u] + p1[u] * ss[u]);
  }
  _Float16* dst = Kr + (size_t)row * KVD + h * HD + 4 * g;
  *(half4*)dst = o1;
  *(half4*)(dst + 64) = o2;
}

// ---------------------------------------------------------------------------
// vtprep: fp32 V [b*S][KVD] -> f16 Vt [b][kvh][d][s] (transposed).
// 64x64 tile via LDS.
// ---------------------------------------------------------------------------
__global__ __launch_bounds__(256) void vtprep(
    const float* __restrict__ v, _Float16* __restrict__ Vt)
{
  __shared__ float Ts[64][68];
  const int s0 = blockIdx.x * 64, c0 = blockIdx.y * 64;
  const int tid = threadIdx.x;
#pragma unroll
  for (int it = 0; it < 4; ++it) {
    const int r = it * 16 + (tid >> 4);
    *(float4*)&Ts[r][(tid & 15) * 4] =
        *(const float4*)&v[(size_t)(s0 + r) * KVD + c0 + (tid & 15) * 4];
  }
  __syncthreads();
  const int dr = tid >> 2, sg = tid & 3;
  const int d = c0 + dr;
  const int kvh = d >> 7, dd = d & 127;
  const int bb = s0 >> 11, sl = s0 & (S_LEN - 1);
  half8 t0, t1;
#pragma unroll
  for (int kk = 0; kk < 8; ++kk) t0[kk] = (_Float16)Ts[sg * 16 + kk][dr];
#pragma unroll
  for (int kk = 0; kk < 8; ++kk) t1[kk] = (_Float16)Ts[sg * 16 + 8 + kk][dr];
  _Float16* dst = Vt + ((size_t)(bb * NKV + kvh) * HD + dd) * S_LEN + sl + sg * 16;
  *(half8*)dst = t0;
  *(half8*)(dst + 8) = t1;
}

// ---------------------------------------------------------------------------
// MFMA flash attention. Block = (64 q-rows, head, batch), 4 waves; wave owns
// 16 q-rows. K/V tiles (64 kv) staged in LDS; QK^T and PV via
// mfma_f32_16x16x32_f16. Online softmax in C-layout (row=quad*4+reg,
// col=lane&15); P transits C-layout -> A-layout via wave-private LDS with
// paired-lane packed b32 writes. Causal: trip count qt+1 (uniform across
// waves), mask only the diagonal tile.
// ---------------------------------------------------------------------------
__global__ __launch_bounds__(256, 4) void attn_mfma(
    const _Float16* __restrict__ Qr, const _Float16* __restrict__ Kr,
    const _Float16* __restrict__ Vt, float* __restrict__ aout)
{
  __shared__ _Float16 Ks[64][136];   // [kv][d], pad 8: 272B rows, odd superbank
  __shared__ _Float16 Vs[128][72];   // [d][kv], pad 8: 144B rows
  __shared__ _Float16 Ps[4][16][72]; // per-wave P buffer [q][kv]

  const int tid = threadIdx.x;
  const int wave = tid >> 6, lane = tid & 63;
  const int l16 = lane & 15, quad = lane >> 4;
  const int qt = (int)gridDim.x - 1 - (int)blockIdx.x; // heaviest tiles first
  const int h = blockIdx.y, b = blockIdx.z;
  const int kvh = h >> 2; // N_REP = 4
  const int q0 = qt * 64 + wave * 16;

  // Q A-frags, register resident for the whole block (pre-scaled in qprep)
  half8 qf[4];
  {
    const _Float16* qp = Qr + (size_t)(b * S_LEN + q0 + l16) * DMODEL + h * HD + quad * 8;
#pragma unroll
    for (int c = 0; c < 4; ++c) qf[c] = *(const half8*)(qp + c * 32);
  }

  floatx4 o[8];
#pragma unroll
  for (int d = 0; d < 8; ++d) o[d] = (floatx4){0.f, 0.f, 0.f, 0.f};
  float m_run[4] = {-3e38f, -3e38f, -3e38f, -3e38f};
  float l_run[4] = {0.f, 0.f, 0.f, 0.f};

  // staging assignments
  const int skr = tid >> 2;            // K row 0..63
  const int skc = (tid & 3) * 32;      // K col group
  const _Float16* kgp = Kr + (size_t)(b * S_LEN + skr) * KVD + kvh * HD + skc;
  const int svr = tid >> 1;            // V d-row 0..127
  const int svc = (tid & 1) * 32;      // V kv col group
  const _Float16* vgp = Vt + ((size_t)(b * NKV + kvh) * HD + svr) * S_LEN + svc;

  for (int kt = 0; kt <= qt; ++kt) {
    const int k0 = kt * 64;
    __syncthreads(); // previous-iter frag reads complete
    {
      const _Float16* g = kgp + (size_t)k0 * KVD;
      _Float16* dst = &Ks[skr][skc];
#pragma unroll
      for (int u = 0; u < 4; ++u)
        *(half8*)(dst + u * 8) = *(const half8*)(g + u * 8);
    }
    {
      const _Float16* g = vgp + k0;
      _Float16* dst = &Vs[svr][svc];
#pragma unroll
      for (int u = 0; u < 4; ++u)
        *(half8*)(dst + u * 8) = *(const half8*)(g + u * 8);
    }
    __syncthreads();

    // ---- scores: S = Q K^T (pre-scaled, base-2 domain) ----
    floatx4 s[4];
#pragma unroll
    for (int i = 0; i < 4; ++i) {
      s[i] = (floatx4){0.f, 0.f, 0.f, 0.f};
#pragma unroll
      for (int c = 0; c < 4; ++c) {
        const half8 kf = *(const half8*)&Ks[i * 16 + l16][quad * 8 + c * 32];
        s[i] = __builtin_amdgcn_mfma_f32_16x16x32_f16(qf[c], kf, s[i], 0, 0, 0);
      }
    }

    // ---- causal mask (diagonal tile only) ----
    if (kt == qt) {
#pragma unroll
      for (int i = 0; i < 4; ++i) {
        const int kpos = k0 + i * 16 + l16;
#pragma unroll
        for (int r = 0; r < 4; ++r)
          if (kpos > q0 + quad * 4 + r) s[i][r] = -3.0e38f;
      }
    }

    // ---- online softmax (rows r live in 16-lane groups) ----
    float p[4][4];
#pragma unroll
    for (int r = 0; r < 4; ++r) {
      float rm = fmaxf(fmaxf(s[0][r], s[1][r]), fmaxf(s[2][r], s[3][r]));
      rm = fmaxf(rm, __shfl_xor(rm, 1));
      rm = fmaxf(rm, __shfl_xor(rm, 2));
      rm = fmaxf(rm, __shfl_xor(rm, 4));
      rm = fmaxf(rm, __shfl_xor(rm, 8));
      const float mnew = fmaxf(m_run[r], rm);
      const float alpha = exp2f(m_run[r] - mnew);
      m_run[r] = mnew;
      float rs = 0.f;
#pragma unroll
      for (int i = 0; i < 4; ++i) { p[i][r] = exp2f(s[i][r] - mnew); rs += p[i][r]; }
      rs += __shfl_xor(rs, 1);
      rs += __shfl_xor(rs, 2);
      rs += __shfl_xor(rs, 4);
      rs += __shfl_xor(rs, 8);
      l_run[r] = l_run[r] * alpha + rs;
#pragma unroll
      for (int d = 0; d < 8; ++d) o[d][r] *= alpha;
    }

    // ---- P: C-layout -> A-layout via wave-private LDS (packed b32 writes) ----
    const int odd = l16 & 1;
    const int cbase = l16 & 14;
#pragma unroll
    for (int i = 0; i < 4; ++i) {
#pragma unroll
      for (int rr = 0; rr < 2; ++rr) {
        const float send = odd ? p[i][rr] : p[i][2 + rr];
        const float recv = __shfl_xor(send, 1);
        const float lo = odd ? recv : p[i][rr];      // even column value
        const float hi = odd ? p[i][2 + rr] : recv;  // odd column value
        *(half2v*)&Ps[wave][quad * 4 + 2 * odd + rr][i * 16 + cbase] = pack2h(lo, hi);
      }
    }
    const half8 pf0 = *(const half8*)&Ps[wave][l16][quad * 8];
    const half8 pf1 = *(const half8*)&Ps[wave][l16][32 + quad * 8];

    // ---- O += P V ----
#pragma unroll
    for (int d = 0; d < 8; ++d) {
      const half8 vf0 = *(const half8*)&Vs[d * 16 + l16][quad * 8];
      const half8 vf1 = *(const half8*)&Vs[d * 16 + l16][32 + quad * 8];
      o[d] = __builtin_amdgcn_mfma_f32_16x16x32_f16(pf0, vf0, o[d], 0, 0, 0);
      o[d] = __builtin_amdgcn_mfma_f32_16x16x32_f16(pf1, vf1, o[d], 0, 0, 0);
    }
  }

  // ---- epilogue ----
  float inv[4];
#pragma unroll
  for (int r = 0; r < 4; ++r) inv[r] = 1.0f / l_run[r];
#pragma unroll
  for (int d = 0; d < 8; ++d)
#pragma unroll
    for (int r = 0; r < 4; ++r)
      aout[(size_t)(b * S_LEN + q0 + quad * 4 + r) * DMODEL + h * HD + d * 16 + l16] =
          o[d][r] * inv[r];
}

// ---------------------------------------------------------------------------
extern "C" void kernel_launch(void* const* d_in, const int* in_sizes, int n_in,
                              void* d_out, int out_size, void* d_ws, size_t ws_size,
                              hipStream_t stream) {
  const float* hs   = (const float*)d_in[0];
  const float* cosp = (const float*)d_in[2];
  const float* sinp = (const float*)d_in[3];
  const float* Wq   = (const float*)d_in[4];
  const float* Wk   = (const float*)d_in[5];
  const float* Wv   = (const float*)d_in[6];
  const float* Wo   = (const float*)d_in[7];
  float* out = (float*)d_out;

  // ws layout (75.5 MB): q fp32 | k fp32 | v fp32 | Qr f16 | Kr f16 | Vt f16
  float* q    = (float*)d_ws;
  float* kbuf = q + (size_t)MROWS * DMODEL;
  float* vbuf = kbuf + (size_t)MROWS * KVD;
  _Float16* Qr = (_Float16*)(vbuf + (size_t)MROWS * KVD);
  _Float16* Kr = Qr + (size_t)MROWS * DMODEL;
  _Float16* Vt = Kr + (size_t)MROWS * KVD;
  float* ao = q; // q fp32 is dead after qprep; reuse for attention output

  dim3 blk(256);
  gemm_bf16<<<dim3(DMODEL / 128, MROWS / 128), blk, 0, stream>>>(hs, Wq, q,    MROWS, DMODEL, DMODEL);
  gemm_bf16<<<dim3(KVD / 128, MROWS / 128),    blk, 0, stream>>>(hs, Wk, kbuf, MROWS, KVD,    DMODEL);
  gemm_bf16<<<dim3(KVD / 128, MROWS / 128),    blk, 0, stream>>>(hs, Wv, vbuf, MROWS, KVD,    DMODEL);
  qprep<<<MROWS, blk, 0, stream>>>(q, cosp, sinp, Qr);
  kprep<<<MROWS / 4, blk, 0, stream>>>(kbuf, cosp, sinp, Kr);
  vtprep<<<dim3(MROWS / 64, KVD / 64), blk, 0, stream>>>(vbuf, Vt);
  attn_mfma<<<dim3(S_LEN / 64, NH, BATCH), blk, 0, stream>>>(Qr, Kr, Vt, ao);
  gemm_bf16<<<dim3(DMODEL / 128, MROWS / 128), blk, 0, stream>>>(ao, Wo, out, MROWS, DMODEL, DMODEL);
}

// Round 5
// 513.180 us; speedup vs baseline: 4.6259x; 1.4355x over previous
//
#include <hip/hip_runtime.h>
#include <cstddef>
#include <cstdint>

#define S_LEN 2048
#define DMODEL 2048
#define NH 16
#define NKV 4
#define HD 128
#define BATCH 2
#define MROWS (BATCH * S_LEN) /* 4096 */
#define KVD (NKV * HD)        /* 512 */

typedef __attribute__((ext_vector_type(8))) short bf16x8;
typedef __attribute__((ext_vector_type(4))) float floatx4;
typedef __attribute__((ext_vector_type(8))) _Float16 half8;
typedef __attribute__((ext_vector_type(4))) _Float16 half4;
typedef __attribute__((ext_vector_type(2))) _Float16 half2v;

#define QSCALE 0.1275310255f /* log2(e)/sqrt(128): folds softmax scale + exp2 conversion */

__device__ inline short f2bf(float f) {
  union { float f; unsigned u; } v; v.f = f;
  unsigned r = v.u + 0x7FFFu + ((v.u >> 16) & 1u); // RNE
  return (short)(r >> 16);
}

__device__ inline half2v pack2h(float lo, float hi) {
  union { decltype(__builtin_amdgcn_cvt_pkrtz(0.f, 0.f)) raw; half2v h; } u;
  u.raw = __builtin_amdgcn_cvt_pkrtz(lo, hi);
  return u.h;
}

// CK-style address-space cast idiom for direct global->LDS DMA (16B/lane).
__device__ __forceinline__ void glds16(const void* g, void* l) {
  __builtin_amdgcn_global_load_lds(
      reinterpret_cast<const int __attribute__((address_space(1)))*>(
          reinterpret_cast<uintptr_t>(g)),
      reinterpret_cast<int __attribute__((address_space(3)))*>(
          reinterpret_cast<uintptr_t>(l)),
      16, 0, 0);
}

// ---------------------------------------------------------------------------
// cast_bf16: fp32 -> bf16 elementwise (8 elems/thread).
// ---------------------------------------------------------------------------
__global__ __launch_bounds__(256) void cast_bf16(
    const float* __restrict__ x, short* __restrict__ y)
{
  const size_t i = ((size_t)blockIdx.x * 256 + threadIdx.x) * 8;
  const float4 a = *(const float4*)(x + i);
  const float4 b = *(const float4*)(x + i + 4);
  bf16x8 o;
  o[0] = f2bf(a.x); o[1] = f2bf(a.y); o[2] = f2bf(a.z); o[3] = f2bf(a.w);
  o[4] = f2bf(b.x); o[5] = f2bf(b.y); o[6] = f2bf(b.z); o[7] = f2bf(b.w);
  *(bf16x8*)(y + i) = o;
}

// ---------------------------------------------------------------------------
// tcast: W fp32 [2048][N] -> Wt bf16 [N][2048] (transpose + cast), 64x64 tile.
// ---------------------------------------------------------------------------
__global__ __launch_bounds__(256) void tcast(
    const float* __restrict__ W, short* __restrict__ Wt, int N)
{
  __shared__ float Ts[64][65];
  const int n0 = blockIdx.x * 64, k0 = blockIdx.y * 64;
  const int tid = threadIdx.x;
#pragma unroll
  for (int it = 0; it < 4; ++it) {
    const int r = it * 16 + (tid >> 4);
    *(float4*)&Ts[r][(tid & 15) * 4] =
        *(const float4*)&W[(size_t)(k0 + r) * N + n0 + (tid & 15) * 4];
  }
  __syncthreads();
  const int n = tid >> 2, kg = (tid & 3) * 16;
  bf16x8 o0, o1;
#pragma unroll
  for (int e = 0; e < 8; ++e) o0[e] = f2bf(Ts[kg + e][n]);
#pragma unroll
  for (int e = 0; e < 8; ++e) o1[e] = f2bf(Ts[kg + 8 + e][n]);
  short* dst = Wt + (size_t)(n0 + n) * DMODEL + k0 + kg;
  *(bf16x8*)dst = o0;
  *(bf16x8*)(dst + 8) = o1;
}

// ---------------------------------------------------------------------------
// m97-style GEMM: C[M,N] = A[M,K] @ Bt[N,K]^T, A/Bt bf16 in global, staged via
// global_load_lds (16B/lane DMA, zero staging VALU). 128x128 tile, BK=64,
// 4 waves, wave = 64x64 quadrant of 4x4 mfma_f32_16x16x32_bf16.
// LDS [128][64] shorts unpadded (DMA requires exact lane order).
// OUTF16: cast C to f16 (q/k/v path) else fp32 (final output).
// ---------------------------------------------------------------------------
template <bool OUTF16>
__global__ __launch_bounds__(256) void gemm_glds(
    const short* __restrict__ A, const short* __restrict__ Bt,
    void* __restrict__ Cv, int M, int N, int K)
{
  __shared__ short As[128 * 64];
  __shared__ short Bs[128 * 64];

  const int tid = threadIdx.x;
  const int wave = tid >> 6, lane = tid & 63;
  const int l16 = lane & 15, quad = lane >> 4;
  const int wm = (wave & 1) * 64, wn = (wave >> 1) * 64;
  const int m0 = blockIdx.y * 128, n0 = blockIdx.x * 128;

  // DMA mapping: wave w, instr u stages rows (w*4+u)*8 + lane/8, cols (lane&7)*8
  const short* Ab = A + (size_t)(m0 + wave * 32 + (lane >> 3)) * K + ((lane & 7) << 3);
  const short* Bb = Bt + (size_t)(n0 + wave * 32 + (lane >> 3)) * K + ((lane & 7) << 3);
  short* Asw = As + wave * 32 * 64;
  short* Bsw = Bs + wave * 32 * 64;

  floatx4 acc[4][4];
#pragma unroll
  for (int i = 0; i < 4; ++i)
#pragma unroll
    for (int j = 0; j < 4; ++j)
#pragma unroll
      for (int r = 0; r < 4; ++r) acc[i][j][r] = 0.f;

  for (int k0 = 0; k0 < K; k0 += 64) {
    __syncthreads(); // prior frag reads complete before DMA overwrites
#pragma unroll
    for (int u = 0; u < 4; ++u) {
      glds16(Ab + (size_t)(u * 8) * K + k0, Asw + u * 8 * 64);
      glds16(Bb + (size_t)(u * 8) * K + k0, Bsw + u * 8 * 64);
    }
    __syncthreads(); // vmcnt(0) drain: LDS tiles ready
#pragma unroll
    for (int c = 0; c < 2; ++c) {
      bf16x8 af[4], bf[4];
#pragma unroll
      for (int i = 0; i < 4; ++i)
        af[i] = *(const bf16x8*)&As[(wm + i * 16 + l16) * 64 + c * 32 + quad * 8];
#pragma unroll
      for (int j = 0; j < 4; ++j)
        bf[j] = *(const bf16x8*)&Bs[(wn + j * 16 + l16) * 64 + c * 32 + quad * 8];
#pragma unroll
      for (int i = 0; i < 4; ++i)
#pragma unroll
        for (int j = 0; j < 4; ++j)
          acc[i][j] = __builtin_amdgcn_mfma_f32_16x16x32_bf16(af[i], bf[j], acc[i][j], 0, 0, 0);
    }
  }

#pragma unroll
  for (int i = 0; i < 4; ++i)
#pragma unroll
    for (int r = 0; r < 4; ++r) {
      const int row = m0 + wm + i * 16 + (quad << 2) + r;
      if (OUTF16) {
        _Float16* cr = (_Float16*)Cv + (size_t)row * N + n0 + wn + l16;
#pragma unroll
        for (int j = 0; j < 4; ++j) cr[j * 16] = (_Float16)acc[i][j][r];
      } else {
        float* cr = (float*)Cv + (size_t)row * N + n0 + wn + l16;
#pragma unroll
        for (int j = 0; j < 4; ++j) cr[j * 16] = acc[i][j][r];
      }
    }
}

// ---------------------------------------------------------------------------
// rope_q: in-place RoPE on f16 q [MROWS][DMODEL], pre-scaled by QSCALE.
// One row per block; read row -> barrier -> write row (in-place safe).
// ---------------------------------------------------------------------------
__global__ __launch_bounds__(256) void rope_q(
    _Float16* __restrict__ qh, const float* __restrict__ cosp,
    const float* __restrict__ sinp)
{
  const int row = blockIdx.x, sl = row & (S_LEN - 1);
  const int h = threadIdx.x >> 4, g = threadIdx.x & 15;
  _Float16* base = qh + (size_t)row * DMODEL + h * HD;
  const half8 x = *(const half8*)(base + 8 * g);
  const float4 c4 = *(const float4*)&cosp[sl * 64 + 4 * g];
  const float4 s4 = *(const float4*)&sinp[sl * 64 + 4 * g];
  const float p1[4] = {(float)x[0], (float)x[2], (float)x[4], (float)x[6]};
  const float p2[4] = {(float)x[1], (float)x[3], (float)x[5], (float)x[7]};
  const float cc[4] = {c4.x, c4.y, c4.z, c4.w};
  const float ss[4] = {s4.x, s4.y, s4.z, s4.w};
  __syncthreads(); // all reads of the row complete before any write
  half4 o1, o2;
#pragma unroll
  for (int u = 0; u < 4; ++u) {
    o1[u] = (_Float16)((p1[u] * cc[u] - p2[u] * ss[u]) * QSCALE);
    o2[u] = (_Float16)((p2[u] * cc[u] + p1[u] * ss[u]) * QSCALE);
  }
  *(half4*)(base + 4 * g) = o1;
  *(half4*)(base + 64 + 4 * g) = o2;
}

// ---------------------------------------------------------------------------
// rope_k: in-place RoPE on f16 k [MROWS][KVD], no scale. 4 rows per block.
// ---------------------------------------------------------------------------
__global__ __launch_bounds__(256) void rope_k(
    _Float16* __restrict__ kh, const float* __restrict__ cosp,
    const float* __restrict__ sinp)
{
  const int row = blockIdx.x * 4 + (threadIdx.x >> 6);
  const int sl = row & (S_LEN - 1);
  const int t = threadIdx.x & 63;
  const int h = t >> 4, g = t & 15;
  _Float16* base = kh + (size_t)row * KVD + h * HD;
  const half8 x = *(const half8*)(base + 8 * g);
  const float4 c4 = *(const float4*)&cosp[sl * 64 + 4 * g];
  const float4 s4 = *(const float4*)&sinp[sl * 64 + 4 * g];
  const float p1[4] = {(float)x[0], (float)x[2], (float)x[4], (float)x[6]};
  const float p2[4] = {(float)x[1], (float)x[3], (float)x[5], (float)x[7]};
  const float cc[4] = {c4.x, c4.y, c4.z, c4.w};
  const float ss[4] = {s4.x, s4.y, s4.z, s4.w};
  __syncthreads();
  half4 o1, o2;
#pragma unroll
  for (int u = 0; u < 4; ++u) {
    o1[u] = (_Float16)(p1[u] * cc[u] - p2[u] * ss[u]);
    o2[u] = (_Float16)(p2[u] * cc[u] + p1[u] * ss[u]);
  }
  *(half4*)(base + 4 * g) = o1;
  *(half4*)(base + 64 + 4 * g) = o2;
}

// ---------------------------------------------------------------------------
// vtprep: f16 V [b*S][KVD] -> f16 Vt [b][kvh][d][s] (transpose), 64x64 tile.
// ---------------------------------------------------------------------------
__global__ __launch_bounds__(256) void vtprep(
    const _Float16* __restrict__ v, _Float16* __restrict__ Vt)
{
  __shared__ _Float16 Ts[64][72];
  const int s0 = blockIdx.x * 64, c0 = blockIdx.y * 64;
  const int tid = threadIdx.x;
#pragma unroll
  for (int it = 0; it < 4; ++it) {
    const int r = it * 16 + (tid >> 4);
    *(half4*)&Ts[r][(tid & 15) * 4] =
        *(const half4*)&v[(size_t)(s0 + r) * KVD + c0 + (tid & 15) * 4];
  }
  __syncthreads();
  const int dr = tid >> 2, sg = tid & 3;
  const int d = c0 + dr;
  const int kvh = d >> 7, dd = d & 127;
  const int bb = s0 >> 11, sl = s0 & (S_LEN - 1);
  half8 t0, t1;
#pragma unroll
  for (int kk = 0; kk < 8; ++kk) t0[kk] = Ts[sg * 16 + kk][dr];
#pragma unroll
  for (int kk = 0; kk < 8; ++kk) t1[kk] = Ts[sg * 16 + 8 + kk][dr];
  _Float16* dst = Vt + ((size_t)(bb * NKV + kvh) * HD + dd) * S_LEN + sl + sg * 16;
  *(half8*)dst = t0;
  *(half8*)(dst + 8) = t1;
}

// ---------------------------------------------------------------------------
// MFMA flash attention (round-4 verified structure; output now bf16).
// ---------------------------------------------------------------------------
__global__ __launch_bounds__(256, 4) void attn_mfma(
    const _Float16* __restrict__ Qr, const _Float16* __restrict__ Kr,
    const _Float16* __restrict__ Vt, short* __restrict__ aout)
{
  __shared__ _Float16 Ks[64][136];
  __shared__ _Float16 Vs[128][72];
  __shared__ _Float16 Ps[4][16][72];

  const int tid = threadIdx.x;
  const int wave = tid >> 6, lane = tid & 63;
  const int l16 = lane & 15, quad = lane >> 4;
  const int qt = (int)gridDim.x - 1 - (int)blockIdx.x; // heaviest tiles first
  const int h = blockIdx.y, b = blockIdx.z;
  const int kvh = h >> 2;
  const int q0 = qt * 64 + wave * 16;

  half8 qf[4];
  {
    const _Float16* qp = Qr + (size_t)(b * S_LEN + q0 + l16) * DMODEL + h * HD + quad * 8;
#pragma unroll
    for (int c = 0; c < 4; ++c) qf[c] = *(const half8*)(qp + c * 32);
  }

  floatx4 o[8];
#pragma unroll
  for (int d = 0; d < 8; ++d) o[d] = (floatx4){0.f, 0.f, 0.f, 0.f};
  float m_run[4] = {-3e38f, -3e38f, -3e38f, -3e38f};
  float l_run[4] = {0.f, 0.f, 0.f, 0.f};

  const int skr = tid >> 2;
  const int skc = (tid & 3) * 32;
  const _Float16* kgp = Kr + (size_t)(b * S_LEN + skr) * KVD + kvh * HD + skc;
  const int svr = tid >> 1;
  const int svc = (tid & 1) * 32;
  const _Float16* vgp = Vt + ((size_t)(b * NKV + kvh) * HD + svr) * S_LEN + svc;

  for (int kt = 0; kt <= qt; ++kt) {
    const int k0 = kt * 64;
    __syncthreads();
    {
      const _Float16* g = kgp + (size_t)k0 * KVD;
      _Float16* dst = &Ks[skr][skc];
#pragma unroll
      for (int u = 0; u < 4; ++u)
        *(half8*)(dst + u * 8) = *(const half8*)(g + u * 8);
    }
    {
      const _Float16* g = vgp + k0;
      _Float16* dst = &Vs[svr][svc];
#pragma unroll
      for (int u = 0; u < 4; ++u)
        *(half8*)(dst + u * 8) = *(const half8*)(g + u * 8);
    }
    __syncthreads();

    floatx4 s[4];
#pragma unroll
    for (int i = 0; i < 4; ++i) {
      s[i] = (floatx4){0.f, 0.f, 0.f, 0.f};
#pragma unroll
      for (int c = 0; c < 4; ++c) {
        const half8 kf = *(const half8*)&Ks[i * 16 + l16][quad * 8 + c * 32];
        s[i] = __builtin_amdgcn_mfma_f32_16x16x32_f16(qf[c], kf, s[i], 0, 0, 0);
      }
    }

    if (kt == qt) {
#pragma unroll
      for (int i = 0; i < 4; ++i) {
        const int kpos = k0 + i * 16 + l16;
#pragma unroll
        for (int r = 0; r < 4; ++r)
          if (kpos > q0 + quad * 4 + r) s[i][r] = -3.0e38f;
      }
    }

    float p[4][4];
#pragma unroll
    for (int r = 0; r < 4; ++r) {
      float rm = fmaxf(fmaxf(s[0][r], s[1][r]), fmaxf(s[2][r], s[3][r]));
      rm = fmaxf(rm, __shfl_xor(rm, 1));
      rm = fmaxf(rm, __shfl_xor(rm, 2));
      rm = fmaxf(rm, __shfl_xor(rm, 4));
      rm = fmaxf(rm, __shfl_xor(rm, 8));
      const float mnew = fmaxf(m_run[r], rm);
      const float alpha = exp2f(m_run[r] - mnew);
      m_run[r] = mnew;
      float rs = 0.f;
#pragma unroll
      for (int i = 0; i < 4; ++i) { p[i][r] = exp2f(s[i][r] - mnew); rs += p[i][r]; }
      rs += __shfl_xor(rs, 1);
      rs += __shfl_xor(rs, 2);
      rs += __shfl_xor(rs, 4);
      rs += __shfl_xor(rs, 8);
      l_run[r] = l_run[r] * alpha + rs;
#pragma unroll
      for (int d = 0; d < 8; ++d) o[d][r] *= alpha;
    }

    const int odd = l16 & 1;
    const int cbase = l16 & 14;
#pragma unroll
    for (int i = 0; i < 4; ++i) {
#pragma unroll
      for (int rr = 0; rr < 2; ++rr) {
        const float send = odd ? p[i][rr] : p[i][2 + rr];
        const float recv = __shfl_xor(send, 1);
        const float lo = odd ? recv : p[i][rr];
        const float hi = odd ? p[i][2 + rr] : recv;
        *(half2v*)&Ps[wave][quad * 4 + 2 * odd + rr][i * 16 + cbase] = pack2h(lo, hi);
      }
    }
    const half8 pf0 = *(const half8*)&Ps[wave][l16][quad * 8];
    const half8 pf1 = *(const half8*)&Ps[wave][l16][32 + quad * 8];

#pragma unroll
    for (int d = 0; d < 8; ++d) {
      const half8 vf0 = *(const half8*)&Vs[d * 16 + l16][quad * 8];
      const half8 vf1 = *(const half8*)&Vs[d * 16 + l16][32 + quad * 8];
      o[d] = __builtin_amdgcn_mfma_f32_16x16x32_f16(pf0, vf0, o[d], 0, 0, 0);
      o[d] = __builtin_amdgcn_mfma_f32_16x16x32_f16(pf1, vf1, o[d], 0, 0, 0);
    }
  }

  float inv[4];
#pragma unroll
  for (int r = 0; r < 4; ++r) inv[r] = 1.0f / l_run[r];
#pragma unroll
  for (int d = 0; d < 8; ++d)
#pragma unroll
    for (int r = 0; r < 4; ++r)
      aout[(size_t)(b * S_LEN + q0 + quad * 4 + r) * DMODEL + h * HD + d * 16 + l16] =
          f2bf(o[d][r] * inv[r]);
}

// ---------------------------------------------------------------------------
extern "C" void kernel_launch(void* const* d_in, const int* in_sizes, int n_in,
                              void* d_out, int out_size, void* d_ws, size_t ws_size,
                              hipStream_t stream) {
  const float* hs   = (const float*)d_in[0];
  const float* cosp = (const float*)d_in[2];
  const float* sinp = (const float*)d_in[3];
  const float* Wq   = (const float*)d_in[4];
  const float* Wk   = (const float*)d_in[5];
  const float* Wv   = (const float*)d_in[6];
  const float* Wo   = (const float*)d_in[7];
  float* out = (float*)d_out;

  // ws layout (54 MB):
  //   hsb bf16 16.8M (dead after gemmV -> aliased by ao bf16)
  //   W8 bf16 8.4M (Wqt, later Wot) | W9 bf16 2.1M (Wkt, later Wvt)
  //   qh f16 16.8M (RoPE in-place) | kh f16 4.2M (in-place) | vh f16 4.2M | Vt f16 4.2M
  char* w = (char*)d_ws;
  short*    hsb = (short*)w;
  short*    W8  = (short*)(w + 16777216);
  short*    W9  = (short*)(w + 25165824);
  _Float16* qh  = (_Float16*)(w + 27262976);
  _Float16* kh  = (_Float16*)(w + 44040192);
  _Float16* vh  = (_Float16*)(w + 48234496);
  _Float16* Vt  = (_Float16*)(w + 52428800);
  short*    ao  = hsb; // safe alias: hsb dead after the V GEMM

  dim3 blk(256);
  cast_bf16<<<MROWS * DMODEL / (8 * 256), blk, 0, stream>>>(hs, hsb);
  tcast<<<dim3(DMODEL / 64, DMODEL / 64), blk, 0, stream>>>(Wq, W8, DMODEL);
  gemm_glds<true><<<dim3(DMODEL / 128, MROWS / 128), blk, 0, stream>>>(hsb, W8, qh, MROWS, DMODEL, DMODEL);
  tcast<<<dim3(KVD / 64, DMODEL / 64), blk, 0, stream>>>(Wk, W9, KVD);
  gemm_glds<true><<<dim3(KVD / 128, MROWS / 128), blk, 0, stream>>>(hsb, W9, kh, MROWS, KVD, DMODEL);
  tcast<<<dim3(KVD / 64, DMODEL / 64), blk, 0, stream>>>(Wv, W9, KVD);
  gemm_glds<true><<<dim3(KVD / 128, MROWS / 128), blk, 0, stream>>>(hsb, W9, vh, MROWS, KVD, DMODEL);
  rope_q<<<MROWS, blk, 0, stream>>>(qh, cosp, sinp);
  rope_k<<<MROWS / 4, blk, 0, stream>>>(kh, cosp, sinp);
  vtprep<<<dim3(MROWS / 64, KVD / 64), blk, 0, stream>>>(vh, Vt);
  attn_mfma<<<dim3(S_LEN / 64, NH, BATCH), blk, 0, stream>>>(qh, kh, Vt, ao);
  tcast<<<dim3(DMODEL / 64, DMODEL / 64), blk, 0, stream>>>(Wo, W8, DMODEL);
  gemm_glds<false><<<dim3(DMODEL / 128, MROWS / 128), blk, 0, stream>>>(ao, W8, out, MROWS, DMODEL, DMODEL);
}

// Round 6
// 494.271 us; speedup vs baseline: 4.8029x; 1.0383x over previous
//
#include <hip/hip_runtime.h>
#include <cstddef>
#include <cstdint>

#define S_LEN 2048
#define DMODEL 2048
#define NH 16
#define NKV 4
#define HD 128
#define BATCH 2
#define MROWS (BATCH * S_LEN) /* 4096 */
#define KVD (NKV * HD)        /* 512 */
#define QKVSTR 3072           /* fused qkv row stride (f16) */

typedef __attribute__((ext_vector_type(8))) short bf16x8;
typedef __attribute__((ext_vector_type(4))) float floatx4;
typedef __attribute__((ext_vector_type(8))) _Float16 half8;
typedef __attribute__((ext_vector_type(4))) _Float16 half4;
typedef __attribute__((ext_vector_type(2))) _Float16 half2v;

#define QSCALE 0.1275310255f /* log2(e)/sqrt(128): folds softmax scale + exp2 conversion */

__device__ inline short f2bf(float f) {
  union { float f; unsigned u; } v; v.f = f;
  unsigned r = v.u + 0x7FFFu + ((v.u >> 16) & 1u); // RNE
  return (short)(r >> 16);
}

__device__ inline half2v pack2h(float lo, float hi) {
  union { decltype(__builtin_amdgcn_cvt_pkrtz(0.f, 0.f)) raw; half2v h; } u;
  u.raw = __builtin_amdgcn_cvt_pkrtz(lo, hi);
  return u.h;
}

// CK-style address-space cast idiom for direct global->LDS DMA (16B/lane).
__device__ __forceinline__ void glds16(const void* g, void* l) {
  __builtin_amdgcn_global_load_lds(
      reinterpret_cast<const int __attribute__((address_space(1)))*>(
          reinterpret_cast<uintptr_t>(g)),
      reinterpret_cast<int __attribute__((address_space(3)))*>(
          reinterpret_cast<uintptr_t>(l)),
      16, 0, 0);
}

// ---------------------------------------------------------------------------
// cast_bf16: fp32 -> bf16 elementwise (8 elems/thread).
// ---------------------------------------------------------------------------
__global__ __launch_bounds__(256) void cast_bf16(
    const float* __restrict__ x, short* __restrict__ y)
{
  const size_t i = ((size_t)blockIdx.x * 256 + threadIdx.x) * 8;
  const float4 a = *(const float4*)(x + i);
  const float4 b = *(const float4*)(x + i + 4);
  bf16x8 o;
  o[0] = f2bf(a.x); o[1] = f2bf(a.y); o[2] = f2bf(a.z); o[3] = f2bf(a.w);
  o[4] = f2bf(b.x); o[5] = f2bf(b.y); o[6] = f2bf(b.z); o[7] = f2bf(b.w);
  *(bf16x8*)(y + i) = o;
}

// ---------------------------------------------------------------------------
// tcast: W fp32 [2048][N] -> Wt bf16 [N][2048] (transpose + cast), 64x64 tile.
// Wt base may be pre-offset (fused-weight packing).
// ---------------------------------------------------------------------------
__global__ __launch_bounds__(256) void tcast(
    const float* __restrict__ W, short* __restrict__ Wt, int N)
{
  __shared__ float Ts[64][65];
  const int n0 = blockIdx.x * 64, k0 = blockIdx.y * 64;
  const int tid = threadIdx.x;
#pragma unroll
  for (int it = 0; it < 4; ++it) {
    const int r = it * 16 + (tid >> 4);
    *(float4*)&Ts[r][(tid & 15) * 4] =
        *(const float4*)&W[(size_t)(k0 + r) * N + n0 + (tid & 15) * 4];
  }
  __syncthreads();
  const int n = tid >> 2, kg = (tid & 3) * 16;
  bf16x8 o0, o1;
#pragma unroll
  for (int e = 0; e < 8; ++e) o0[e] = f2bf(Ts[kg + e][n]);
#pragma unroll
  for (int e = 0; e < 8; ++e) o1[e] = f2bf(Ts[kg + 8 + e][n]);
  short* dst = Wt + (size_t)(n0 + n) * DMODEL + k0 + kg;
  *(bf16x8*)dst = o0;
  *(bf16x8*)(dst + 8) = o1;
}

// ---------------------------------------------------------------------------
// m97-style GEMM: C[M,N] = A[M,K] @ Bt[N,K]^T, bf16 operands staged via
// global_load_lds. 128x128 tile, BK=64, 4 waves of 4x4 mfma_f32_16x16x32_bf16.
// ---------------------------------------------------------------------------
template <bool OUTF16>
__global__ __launch_bounds__(256) void gemm_glds(
    const short* __restrict__ A, const short* __restrict__ Bt,
    void* __restrict__ Cv, int M, int N, int K)
{
  __shared__ short As[128 * 64];
  __shared__ short Bs[128 * 64];

  const int tid = threadIdx.x;
  const int wave = tid >> 6, lane = tid & 63;
  const int l16 = lane & 15, quad = lane >> 4;
  const int wm = (wave & 1) * 64, wn = (wave >> 1) * 64;
  const int m0 = blockIdx.y * 128, n0 = blockIdx.x * 128;

  const short* Ab = A + (size_t)(m0 + wave * 32 + (lane >> 3)) * K + ((lane & 7) << 3);
  const short* Bb = Bt + (size_t)(n0 + wave * 32 + (lane >> 3)) * K + ((lane & 7) << 3);
  short* Asw = As + wave * 32 * 64;
  short* Bsw = Bs + wave * 32 * 64;

  floatx4 acc[4][4];
#pragma unroll
  for (int i = 0; i < 4; ++i)
#pragma unroll
    for (int j = 0; j < 4; ++j)
#pragma unroll
      for (int r = 0; r < 4; ++r) acc[i][j][r] = 0.f;

  for (int k0 = 0; k0 < K; k0 += 64) {
    __syncthreads();
#pragma unroll
    for (int u = 0; u < 4; ++u) {
      glds16(Ab + (size_t)(u * 8) * K + k0, Asw + u * 8 * 64);
      glds16(Bb + (size_t)(u * 8) * K + k0, Bsw + u * 8 * 64);
    }
    __syncthreads();
#pragma unroll
    for (int c = 0; c < 2; ++c) {
      bf16x8 af[4], bf[4];
#pragma unroll
      for (int i = 0; i < 4; ++i)
        af[i] = *(const bf16x8*)&As[(wm + i * 16 + l16) * 64 + c * 32 + quad * 8];
#pragma unroll
      for (int j = 0; j < 4; ++j)
        bf[j] = *(const bf16x8*)&Bs[(wn + j * 16 + l16) * 64 + c * 32 + quad * 8];
#pragma unroll
      for (int i = 0; i < 4; ++i)
#pragma unroll
        for (int j = 0; j < 4; ++j)
          acc[i][j] = __builtin_amdgcn_mfma_f32_16x16x32_bf16(af[i], bf[j], acc[i][j], 0, 0, 0);
    }
  }

#pragma unroll
  for (int i = 0; i < 4; ++i)
#pragma unroll
    for (int r = 0; r < 4; ++r) {
      const int row = m0 + wm + i * 16 + (quad << 2) + r;
      if (OUTF16) {
        _Float16* cr = (_Float16*)Cv + (size_t)row * N + n0 + wn + l16;
#pragma unroll
        for (int j = 0; j < 4; ++j) cr[j * 16] = (_Float16)acc[i][j][r];
      } else {
        float* cr = (float*)Cv + (size_t)row * N + n0 + wn + l16;
#pragma unroll
        for (int j = 0; j < 4; ++j) cr[j * 16] = acc[i][j][r];
      }
    }
}

// ---------------------------------------------------------------------------
// rope_q: in-place RoPE on f16 q rows (stride QKVSTR), pre-scaled by QSCALE.
// ---------------------------------------------------------------------------
__global__ __launch_bounds__(256) void rope_q(
    _Float16* __restrict__ qh, const float* __restrict__ cosp,
    const float* __restrict__ sinp)
{
  const int row = blockIdx.x, sl = row & (S_LEN - 1);
  const int h = threadIdx.x >> 4, g = threadIdx.x & 15;
  _Float16* base = qh + (size_t)row * QKVSTR + h * HD;
  const half8 x = *(const half8*)(base + 8 * g);
  const float4 c4 = *(const float4*)&cosp[sl * 64 + 4 * g];
  const float4 s4 = *(const float4*)&sinp[sl * 64 + 4 * g];
  const float p1[4] = {(float)x[0], (float)x[2], (float)x[4], (float)x[6]};
  const float p2[4] = {(float)x[1], (float)x[3], (float)x[5], (float)x[7]};
  const float cc[4] = {c4.x, c4.y, c4.z, c4.w};
  const float ss[4] = {s4.x, s4.y, s4.z, s4.w};
  __syncthreads(); // all reads of the row complete before any write
  half4 o1, o2;
#pragma unroll
  for (int u = 0; u < 4; ++u) {
    o1[u] = (_Float16)((p1[u] * cc[u] - p2[u] * ss[u]) * QSCALE);
    o2[u] = (_Float16)((p2[u] * cc[u] + p1[u] * ss[u]) * QSCALE);
  }
  *(half4*)(base + 4 * g) = o1;
  *(half4*)(base + 64 + 4 * g) = o2;
}

// ---------------------------------------------------------------------------
// rope_k: in-place RoPE on f16 k rows (stride QKVSTR, 4 heads). 4 rows/block.
// ---------------------------------------------------------------------------
__global__ __launch_bounds__(256) void rope_k(
    _Float16* __restrict__ kh, const float* __restrict__ cosp,
    const float* __restrict__ sinp)
{
  const int row = blockIdx.x * 4 + (threadIdx.x >> 6);
  const int sl = row & (S_LEN - 1);
  const int t = threadIdx.x & 63;
  const int h = t >> 4, g = t & 15;
  _Float16* base = kh + (size_t)row * QKVSTR + h * HD;
  const half8 x = *(const half8*)(base + 8 * g);
  const float4 c4 = *(const float4*)&cosp[sl * 64 + 4 * g];
  const float4 s4 = *(const float4*)&sinp[sl * 64 + 4 * g];
  const float p1[4] = {(float)x[0], (float)x[2], (float)x[4], (float)x[6]};
  const float p2[4] = {(float)x[1], (float)x[3], (float)x[5], (float)x[7]};
  const float cc[4] = {c4.x, c4.y, c4.z, c4.w};
  const float ss[4] = {s4.x, s4.y, s4.z, s4.w};
  __syncthreads();
  half4 o1, o2;
#pragma unroll
  for (int u = 0; u < 4; ++u) {
    o1[u] = (_Float16)(p1[u] * cc[u] - p2[u] * ss[u]);
    o2[u] = (_Float16)(p2[u] * cc[u] + p1[u] * ss[u]);
  }
  *(half4*)(base + 4 * g) = o1;
  *(half4*)(base + 64 + 4 * g) = o2;
}

// ---------------------------------------------------------------------------
// vtprep: f16 V rows (stride QKVSTR) -> f16 Vt [b][kvh][d][s], 64x64 tile.
// ---------------------------------------------------------------------------
__global__ __launch_bounds__(256) void vtprep(
    const _Float16* __restrict__ v, _Float16* __restrict__ Vt)
{
  __shared__ _Float16 Ts[64][72];
  const int s0 = blockIdx.x * 64, c0 = blockIdx.y * 64;
  const int tid = threadIdx.x;
#pragma unroll
  for (int it = 0; it < 4; ++it) {
    const int r = it * 16 + (tid >> 4);
    *(half4*)&Ts[r][(tid & 15) * 4] =
        *(const half4*)&v[(size_t)(s0 + r) * QKVSTR + c0 + (tid & 15) * 4];
  }
  __syncthreads();
  const int dr = tid >> 2, sg = tid & 3;
  const int d = c0 + dr;
  const int kvh = d >> 7, dd = d & 127;
  const int bb = s0 >> 11, sl = s0 & (S_LEN - 1);
  half8 t0, t1;
#pragma unroll
  for (int kk = 0; kk < 8; ++kk) t0[kk] = Ts[sg * 16 + kk][dr];
#pragma unroll
  for (int kk = 0; kk < 8; ++kk) t1[kk] = Ts[sg * 16 + 8 + kk][dr];
  _Float16* dst = Vt + ((size_t)(bb * NKV + kvh) * HD + dd) * S_LEN + sl + sg * 16;
  *(half8*)dst = t0;
  *(half8*)(dst + 8) = t1;
}

// ---------------------------------------------------------------------------
// MFMA flash attention v2: block = 128 q-rows x (h,b), 4 waves, wave = 32
// q-rows (2 tiles of 16). K/V frag reads + staging amortized over 2 q-tiles
// -> LDS bytes/work 176->96 KB per 64 q-rows. Trip count 2(qt+1) uniform;
// masking handles diagonal + fully-masked tiles (exp2 underflows to 0).
// LDS 54272 B -> 3 blocks/CU (3x54272 = 162816 <= 163840).
// ---------------------------------------------------------------------------
__global__ __launch_bounds__(256, 3) void attn_mfma(
    const _Float16* __restrict__ Qr, const _Float16* __restrict__ Kr,
    const _Float16* __restrict__ Vt, short* __restrict__ aout)
{
  __shared__ _Float16 Ks[64][136];   // [kv][d], 272B rows (odd superbank)
  __shared__ _Float16 Vs[128][72];   // [d][kv], 144B rows
  __shared__ _Float16 Ps[4][32][72]; // per-wave P buffer [q][kv]

  const int tid = threadIdx.x;
  const int wave = tid >> 6, lane = tid & 63;
  const int l16 = lane & 15, quad = lane >> 4;
  const int qt = (int)gridDim.x - 1 - (int)blockIdx.x; // heaviest blocks first
  const int h = blockIdx.y, b = blockIdx.z;
  const int kvh = h >> 2;
  const int q0w = qt * 128 + wave * 32;

  half8 qf[2][4];
#pragma unroll
  for (int t = 0; t < 2; ++t) {
    const _Float16* qp = Qr + (size_t)(b * S_LEN + q0w + t * 16 + l16) * QKVSTR + h * HD + quad * 8;
#pragma unroll
    for (int c = 0; c < 4; ++c) qf[t][c] = *(const half8*)(qp + c * 32);
  }

  floatx4 o[2][8];
#pragma unroll
  for (int t = 0; t < 2; ++t)
#pragma unroll
    for (int d = 0; d < 8; ++d) o[t][d] = (floatx4){0.f, 0.f, 0.f, 0.f};
  float m_run[2][4], l_run[2][4];
#pragma unroll
  for (int t = 0; t < 2; ++t)
#pragma unroll
    for (int r = 0; r < 4; ++r) { m_run[t][r] = -3e38f; l_run[t][r] = 0.f; }

  const int skr = tid >> 2;
  const int skc = (tid & 3) * 32;
  const _Float16* kgp = Kr + (size_t)(b * S_LEN + skr) * QKVSTR + kvh * HD + skc;
  const int svr = tid >> 1;
  const int svc = (tid & 1) * 32;
  const _Float16* vgp = Vt + ((size_t)(b * NKV + kvh) * HD + svr) * S_LEN + svc;

  const int nkt = 2 * (qt + 1);
  for (int kt = 0; kt < nkt; ++kt) {
    const int k0 = kt * 64;
    __syncthreads();
    {
      const _Float16* g = kgp + (size_t)k0 * QKVSTR;
      _Float16* dst = &Ks[skr][skc];
#pragma unroll
      for (int u = 0; u < 4; ++u)
        *(half8*)(dst + u * 8) = *(const half8*)(g + u * 8);
    }
    {
      const _Float16* g = vgp + k0;
      _Float16* dst = &Vs[svr][svc];
#pragma unroll
      for (int u = 0; u < 4; ++u)
        *(half8*)(dst + u * 8) = *(const half8*)(g + u * 8);
    }
    __syncthreads();

    // ---- scores: both q-tiles share each kf read ----
    floatx4 s[2][4];
#pragma unroll
    for (int t = 0; t < 2; ++t)
#pragma unroll
      for (int i = 0; i < 4; ++i) s[t][i] = (floatx4){0.f, 0.f, 0.f, 0.f};
#pragma unroll
    for (int c = 0; c < 4; ++c)
#pragma unroll
      for (int i = 0; i < 4; ++i) {
        const half8 kf = *(const half8*)&Ks[i * 16 + l16][quad * 8 + c * 32];
        s[0][i] = __builtin_amdgcn_mfma_f32_16x16x32_f16(qf[0][c], kf, s[0][i], 0, 0, 0);
        s[1][i] = __builtin_amdgcn_mfma_f32_16x16x32_f16(qf[1][c], kf, s[1][i], 0, 0, 0);
      }

    // ---- causal mask (diagonal / fully-masked tiles) ----
    if (k0 + 63 > q0w) {
#pragma unroll
      for (int t = 0; t < 2; ++t)
#pragma unroll
        for (int i = 0; i < 4; ++i) {
          const int kpos = k0 + i * 16 + l16;
#pragma unroll
          for (int r = 0; r < 4; ++r)
            if (kpos > q0w + t * 16 + quad * 4 + r) s[t][i][r] = -3.0e38f;
        }
    }

    // ---- online softmax + P write (per q-tile) ----
    const int odd = l16 & 1;
    const int cbase = l16 & 14;
#pragma unroll
    for (int t = 0; t < 2; ++t) {
      float p[4][4];
#pragma unroll
      for (int r = 0; r < 4; ++r) {
        float rm = fmaxf(fmaxf(s[t][0][r], s[t][1][r]), fmaxf(s[t][2][r], s[t][3][r]));
        rm = fmaxf(rm, __shfl_xor(rm, 1));
        rm = fmaxf(rm, __shfl_xor(rm, 2));
        rm = fmaxf(rm, __shfl_xor(rm, 4));
        rm = fmaxf(rm, __shfl_xor(rm, 8));
        const float mnew = fmaxf(m_run[t][r], rm);
        const float alpha = exp2f(m_run[t][r] - mnew);
        m_run[t][r] = mnew;
        float rs = 0.f;
#pragma unroll
        for (int i = 0; i < 4; ++i) { p[i][r] = exp2f(s[t][i][r] - mnew); rs += p[i][r]; }
        rs += __shfl_xor(rs, 1);
        rs += __shfl_xor(rs, 2);
        rs += __shfl_xor(rs, 4);
        rs += __shfl_xor(rs, 8);
        l_run[t][r] = l_run[t][r] * alpha + rs;
#pragma unroll
        for (int d = 0; d < 8; ++d) o[t][d][r] *= alpha;
      }
#pragma unroll
      for (int i = 0; i < 4; ++i) {
#pragma unroll
        for (int rr = 0; rr < 2; ++rr) {
          const float send = odd ? p[i][rr] : p[i][2 + rr];
          const float recv = __shfl_xor(send, 1);
          const float lo = odd ? recv : p[i][rr];
          const float hi = odd ? p[i][2 + rr] : recv;
          *(half2v*)&Ps[wave][t * 16 + quad * 4 + 2 * odd + rr][i * 16 + cbase] = pack2h(lo, hi);
        }
      }
    }

    // ---- O += P V (vf reads shared by both q-tiles) ----
    const half8 pf00 = *(const half8*)&Ps[wave][l16][quad * 8];
    const half8 pf01 = *(const half8*)&Ps[wave][l16][32 + quad * 8];
    const half8 pf10 = *(const half8*)&Ps[wave][16 + l16][quad * 8];
    const half8 pf11 = *(const half8*)&Ps[wave][16 + l16][32 + quad * 8];
#pragma unroll
    for (int d = 0; d < 8; ++d) {
      const half8 vf0 = *(const half8*)&Vs[d * 16 + l16][quad * 8];
      const half8 vf1 = *(const half8*)&Vs[d * 16 + l16][32 + quad * 8];
      o[0][d] = __builtin_amdgcn_mfma_f32_16x16x32_f16(pf00, vf0, o[0][d], 0, 0, 0);
      o[0][d] = __builtin_amdgcn_mfma_f32_16x16x32_f16(pf01, vf1, o[0][d], 0, 0, 0);
      o[1][d] = __builtin_amdgcn_mfma_f32_16x16x32_f16(pf10, vf0, o[1][d], 0, 0, 0);
      o[1][d] = __builtin_amdgcn_mfma_f32_16x16x32_f16(pf11, vf1, o[1][d], 0, 0, 0);
    }
  }

  // ---- epilogue ----
#pragma unroll
  for (int t = 0; t < 2; ++t) {
    float inv[4];
#pragma unroll
    for (int r = 0; r < 4; ++r) inv[r] = 1.0f / l_run[t][r];
#pragma unroll
    for (int d = 0; d < 8; ++d)
#pragma unroll
      for (int r = 0; r < 4; ++r)
        aout[(size_t)(b * S_LEN + q0w + t * 16 + quad * 4 + r) * DMODEL + h * HD + d * 16 + l16] =
            f2bf(o[t][d][r] * inv[r]);
  }
}

// ---------------------------------------------------------------------------
extern "C" void kernel_launch(void* const* d_in, const int* in_sizes, int n_in,
                              void* d_out, int out_size, void* d_ws, size_t ws_size,
                              hipStream_t stream) {
  const float* hs   = (const float*)d_in[0];
  const float* cosp = (const float*)d_in[2];
  const float* sinp = (const float*)d_in[3];
  const float* Wq   = (const float*)d_in[4];
  const float* Wk   = (const float*)d_in[5];
  const float* Wv   = (const float*)d_in[6];
  const float* Wo   = (const float*)d_in[7];
  float* out = (float*)d_out;

  // ws layout (58.7 MB):
  //   hsb bf16 [4096][2048] 16.8M (dead after qkv GEMM -> aliased by ao)
  //   Wt  bf16 [3072][2048] 12.6M (fused Wq|Wk|Wv transposed; later Wo)
  //   qkv f16  [4096][3072] 25.2M (q|k|v fused; RoPE in-place)
  //   Vt  f16  [2][4][128][2048] 4.2M
  char* w = (char*)d_ws;
  short*    hsb = (short*)w;
  short*    Wt  = (short*)(w + 16777216);
  _Float16* qkv = (_Float16*)(w + 29360128);
  _Float16* Vt  = (_Float16*)(w + 54525952);
  short*    ao  = hsb; // safe alias: hsb dead after the fused qkv GEMM

  _Float16* qh = qkv;
  _Float16* kh = qkv + 2048;
  _Float16* vh = qkv + 2560;

  dim3 blk(256);
  cast_bf16<<<MROWS * DMODEL / (8 * 256), blk, 0, stream>>>(hs, hsb);
  tcast<<<dim3(DMODEL / 64, DMODEL / 64), blk, 0, stream>>>(Wq, Wt, DMODEL);
  tcast<<<dim3(KVD / 64, DMODEL / 64), blk, 0, stream>>>(Wk, Wt + (size_t)2048 * DMODEL, KVD);
  tcast<<<dim3(KVD / 64, DMODEL / 64), blk, 0, stream>>>(Wv, Wt + (size_t)2560 * DMODEL, KVD);
  gemm_glds<true><<<dim3(QKVSTR / 128, MROWS / 128), blk, 0, stream>>>(hsb, Wt, qkv, MROWS, QKVSTR, DMODEL);
  rope_q<<<MROWS, blk, 0, stream>>>(qh, cosp, sinp);
  rope_k<<<MROWS / 4, blk, 0, stream>>>(kh, cosp, sinp);
  vtprep<<<dim3(MROWS / 64, KVD / 64), blk, 0, stream>>>(vh, Vt);
  attn_mfma<<<dim3(S_LEN / 128, NH, BATCH), blk, 0, stream>>>(qh, kh, Vt, ao);
  tcast<<<dim3(DMODEL / 64, DMODEL / 64), blk, 0, stream>>>(Wo, Wt, DMODEL);
  gemm_glds<false><<<dim3(DMODEL / 128, MROWS / 128), blk, 0, stream>>>(ao, Wt, out, MROWS, DMODEL, DMODEL);
}

// Round 7
// 394.883 us; speedup vs baseline: 6.0117x; 1.2517x over previous
//
#include <hip/hip_runtime.h>
#include <cstddef>
#include <cstdint>

#define S_LEN 2048
#define DMODEL 2048
#define NH 16
#define NKV 4
#define HD 128
#define BATCH 2
#define MROWS (BATCH * S_LEN) /* 4096 */
#define KVD (NKV * HD)        /* 512 */
#define QKVSTR 3072           /* fused qkv row stride (f16) */
#define NQT (S_LEN / 64)      /* 32 q-tiles of 64 rows */

typedef __attribute__((ext_vector_type(8))) short bf16x8;
typedef __attribute__((ext_vector_type(4))) float floatx4;
typedef __attribute__((ext_vector_type(8))) _Float16 half8;
typedef __attribute__((ext_vector_type(4))) _Float16 half4;
typedef __attribute__((ext_vector_type(2))) _Float16 half2v;

#define QSCALE 0.1275310255f /* log2(e)/sqrt(128): folds softmax scale + exp2 conversion */

__device__ inline short f2bf(float f) {
  union { float f; unsigned u; } v; v.f = f;
  unsigned r = v.u + 0x7FFFu + ((v.u >> 16) & 1u); // RNE
  return (short)(r >> 16);
}

__device__ inline half2v pack2h(float lo, float hi) {
  union { decltype(__builtin_amdgcn_cvt_pkrtz(0.f, 0.f)) raw; half2v h; } u;
  u.raw = __builtin_amdgcn_cvt_pkrtz(lo, hi);
  return u.h;
}

// CK-style address-space cast idiom for direct global->LDS DMA (16B/lane).
__device__ __forceinline__ void glds16(const void* g, void* l) {
  __builtin_amdgcn_global_load_lds(
      reinterpret_cast<const int __attribute__((address_space(1)))*>(
          reinterpret_cast<uintptr_t>(g)),
      reinterpret_cast<int __attribute__((address_space(3)))*>(
          reinterpret_cast<uintptr_t>(l)),
      16, 0, 0);
}

// ---------------------------------------------------------------------------
// cast_bf16: fp32 -> bf16 elementwise (8 elems/thread).
// ---------------------------------------------------------------------------
__global__ __launch_bounds__(256) void cast_bf16(
    const float* __restrict__ x, short* __restrict__ y)
{
  const size_t i = ((size_t)blockIdx.x * 256 + threadIdx.x) * 8;
  const float4 a = *(const float4*)(x + i);
  const float4 b = *(const float4*)(x + i + 4);
  bf16x8 o;
  o[0] = f2bf(a.x); o[1] = f2bf(a.y); o[2] = f2bf(a.z); o[3] = f2bf(a.w);
  o[4] = f2bf(b.x); o[5] = f2bf(b.y); o[6] = f2bf(b.z); o[7] = f2bf(b.w);
  *(bf16x8*)(y + i) = o;
}

// ---------------------------------------------------------------------------
// tcast: W fp32 [2048][N] -> Wt bf16 [N][2048] (transpose + cast), 64x64 tile.
// ---------------------------------------------------------------------------
__global__ __launch_bounds__(256) void tcast(
    const float* __restrict__ W, short* __restrict__ Wt, int N)
{
  __shared__ float Ts[64][65];
  const int n0 = blockIdx.x * 64, k0 = blockIdx.y * 64;
  const int tid = threadIdx.x;
#pragma unroll
  for (int it = 0; it < 4; ++it) {
    const int r = it * 16 + (tid >> 4);
    *(float4*)&Ts[r][(tid & 15) * 4] =
        *(const float4*)&W[(size_t)(k0 + r) * N + n0 + (tid & 15) * 4];
  }
  __syncthreads();
  const int n = tid >> 2, kg = (tid & 3) * 16;
  bf16x8 o0, o1;
#pragma unroll
  for (int e = 0; e < 8; ++e) o0[e] = f2bf(Ts[kg + e][n]);
#pragma unroll
  for (int e = 0; e < 8; ++e) o1[e] = f2bf(Ts[kg + 8 + e][n]);
  short* dst = Wt + (size_t)(n0 + n) * DMODEL + k0 + kg;
  *(bf16x8*)dst = o0;
  *(bf16x8*)(dst + 8) = o1;
}

// ---------------------------------------------------------------------------
// m97-style GEMM: C[M,N] = A[M,K] @ Bt[N,K]^T, bf16 operands staged via
// global_load_lds. 128x128 tile, BK=64, 4 waves of 4x4 mfma_f32_16x16x32_bf16.
// ---------------------------------------------------------------------------
template <bool OUTF16>
__global__ __launch_bounds__(256) void gemm_glds(
    const short* __restrict__ A, const short* __restrict__ Bt,
    void* __restrict__ Cv, int M, int N, int K)
{
  __shared__ short As[128 * 64];
  __shared__ short Bs[128 * 64];

  const int tid = threadIdx.x;
  const int wave = tid >> 6, lane = tid & 63;
  const int l16 = lane & 15, quad = lane >> 4;
  const int wm = (wave & 1) * 64, wn = (wave >> 1) * 64;
  const int m0 = blockIdx.y * 128, n0 = blockIdx.x * 128;

  const short* Ab = A + (size_t)(m0 + wave * 32 + (lane >> 3)) * K + ((lane & 7) << 3);
  const short* Bb = Bt + (size_t)(n0 + wave * 32 + (lane >> 3)) * K + ((lane & 7) << 3);
  short* Asw = As + wave * 32 * 64;
  short* Bsw = Bs + wave * 32 * 64;

  floatx4 acc[4][4];
#pragma unroll
  for (int i = 0; i < 4; ++i)
#pragma unroll
    for (int j = 0; j < 4; ++j)
#pragma unroll
      for (int r = 0; r < 4; ++r) acc[i][j][r] = 0.f;

  for (int k0 = 0; k0 < K; k0 += 64) {
    __syncthreads();
#pragma unroll
    for (int u = 0; u < 4; ++u) {
      glds16(Ab + (size_t)(u * 8) * K + k0, Asw + u * 8 * 64);
      glds16(Bb + (size_t)(u * 8) * K + k0, Bsw + u * 8 * 64);
    }
    __syncthreads();
#pragma unroll
    for (int c = 0; c < 2; ++c) {
      bf16x8 af[4], bf[4];
#pragma unroll
      for (int i = 0; i < 4; ++i)
        af[i] = *(const bf16x8*)&As[(wm + i * 16 + l16) * 64 + c * 32 + quad * 8];
#pragma unroll
      for (int j = 0; j < 4; ++j)
        bf[j] = *(const bf16x8*)&Bs[(wn + j * 16 + l16) * 64 + c * 32 + quad * 8];
#pragma unroll
      for (int i = 0; i < 4; ++i)
#pragma unroll
        for (int j = 0; j < 4; ++j)
          acc[i][j] = __builtin_amdgcn_mfma_f32_16x16x32_bf16(af[i], bf[j], acc[i][j], 0, 0, 0);
    }
  }

#pragma unroll
  for (int i = 0; i < 4; ++i)
#pragma unroll
    for (int r = 0; r < 4; ++r) {
      const int row = m0 + wm + i * 16 + (quad << 2) + r;
      if (OUTF16) {
        _Float16* cr = (_Float16*)Cv + (size_t)row * N + n0 + wn + l16;
#pragma unroll
        for (int j = 0; j < 4; ++j) cr[j * 16] = (_Float16)acc[i][j][r];
      } else {
        float* cr = (float*)Cv + (size_t)row * N + n0 + wn + l16;
#pragma unroll
        for (int j = 0; j < 4; ++j) cr[j * 16] = acc[i][j][r];
      }
    }
}

// ---------------------------------------------------------------------------
// rope_k: in-place RoPE on f16 k rows (stride QKVSTR, 4 heads). 4 rows/block.
// ---------------------------------------------------------------------------
__global__ __launch_bounds__(256) void rope_k(
    _Float16* __restrict__ kh, const float* __restrict__ cosp,
    const float* __restrict__ sinp)
{
  const int row = blockIdx.x * 4 + (threadIdx.x >> 6);
  const int sl = row & (S_LEN - 1);
  const int t = threadIdx.x & 63;
  const int h = t >> 4, g = t & 15;
  _Float16* base = kh + (size_t)row * QKVSTR + h * HD;
  const half8 x = *(const half8*)(base + 8 * g);
  const float4 c4 = *(const float4*)&cosp[sl * 64 + 4 * g];
  const float4 s4 = *(const float4*)&sinp[sl * 64 + 4 * g];
  const float p1[4] = {(float)x[0], (float)x[2], (float)x[4], (float)x[6]};
  const float p2[4] = {(float)x[1], (float)x[3], (float)x[5], (float)x[7]};
  const float cc[4] = {c4.x, c4.y, c4.z, c4.w};
  const float ss[4] = {s4.x, s4.y, s4.z, s4.w};
  __syncthreads();
  half4 o1, o2;
#pragma unroll
  for (int u = 0; u < 4; ++u) {
    o1[u] = (_Float16)(p1[u] * cc[u] - p2[u] * ss[u]);
    o2[u] = (_Float16)(p2[u] * cc[u] + p1[u] * ss[u]);
  }
  *(half4*)(base + 4 * g) = o1;
  *(half4*)(base + 64 + 4 * g) = o2;
}

// ---------------------------------------------------------------------------
// vtprep: f16 V rows (stride QKVSTR) -> f16 Vt [b][kvh][d][s], 64x64 tile.
// ---------------------------------------------------------------------------
__global__ __launch_bounds__(256) void vtprep(
    const _Float16* __restrict__ v, _Float16* __restrict__ Vt)
{
  __shared__ _Float16 Ts[64][72];
  const int s0 = blockIdx.x * 64, c0 = blockIdx.y * 64;
  const int tid = threadIdx.x;
#pragma unroll
  for (int it = 0; it < 4; ++it) {
    const int r = it * 16 + (tid >> 4);
    *(half4*)&Ts[r][(tid & 15) * 4] =
        *(const half4*)&v[(size_t)(s0 + r) * QKVSTR + c0 + (tid & 15) * 4];
  }
  __syncthreads();
  const int dr = tid >> 2, sg = tid & 3;
  const int d = c0 + dr;
  const int kvh = d >> 7, dd = d & 127;
  const int bb = s0 >> 11, sl = s0 & (S_LEN - 1);
  half8 t0, t1;
#pragma unroll
  for (int kk = 0; kk < 8; ++kk) t0[kk] = Ts[sg * 16 + kk][dr];
#pragma unroll
  for (int kk = 0; kk < 8; ++kk) t1[kk] = Ts[sg * 16 + 8 + kk][dr];
  _Float16* dst = Vt + ((size_t)(bb * NKV + kvh) * HD + dd) * S_LEN + sl + sg * 16;
  *(half8*)dst = t0;
  *(half8*)(dst + 8) = t1;
}

// ---------------------------------------------------------------------------
// MFMA flash attention v3: balanced pairing. Block = pair p -> two sequential
// 64-q-row passes (qtA = p, qtB = 31-p): every block runs exactly 33
// K-iterations -> 512 uniform blocks, all resident (2/CU, 16 waves/CU).
// Per-pass structure = round-4 proven v1 tile (wave = 16 q-rows).
// RoPE-Q folded into the Q A-frag register load (k-slices c and c+2 are the
// RoPE pair d, d+64); q input is the raw GEMM output.
// LDS 45056 B.
// ---------------------------------------------------------------------------
__global__ __launch_bounds__(256, 3) void attn_mfma(
    const _Float16* __restrict__ Qh, const _Float16* __restrict__ Kr,
    const _Float16* __restrict__ Vt, const float* __restrict__ cosp,
    const float* __restrict__ sinp, short* __restrict__ aout)
{
  __shared__ _Float16 Ks[64][136];   // [kv][d], 272B rows
  __shared__ _Float16 Vs[128][72];   // [d][kv], 144B rows
  __shared__ _Float16 Ps[4][16][72]; // per-wave P buffer [q][kv]

  const int tid = threadIdx.x;
  const int wave = tid >> 6, lane = tid & 63;
  const int l16 = lane & 15, quad = lane >> 4;
  const int pair = blockIdx.x;
  const int h = blockIdx.y, b = blockIdx.z;
  const int kvh = h >> 2;

  // staging assignments (pass-independent)
  const int skr = tid >> 2;
  const int skc = (tid & 3) * 32;
  const _Float16* kgp = Kr + (size_t)(b * S_LEN + skr) * QKVSTR + kvh * HD + skc;
  const int svr = tid >> 1;
  const int svc = (tid & 1) * 32;
  const _Float16* vgp = Vt + ((size_t)(b * NKV + kvh) * HD + svr) * S_LEN + svc;

  for (int pass = 0; pass < 2; ++pass) {
    const int qt = pass ? (NQT - 1 - pair) : pair;
    const int q0 = qt * 64 + wave * 16;
    const int srow = q0 + l16;

    // ---- Q A-frags with in-register RoPE + scale ----
    // qf[c][j] = roped Q[srow][d = c*32 + quad*8 + j]; pair halves at c, c+2.
    half8 qf[4];
    {
      const _Float16* qraw = Qh + (size_t)(b * S_LEN + srow) * QKVSTR + h * HD;
#pragma unroll
      for (int cc = 0; cc < 2; ++cc) {
        const half8 r0 = *(const half8*)(qraw + cc * 64 + quad * 16);
        const half8 r1 = *(const half8*)(qraw + cc * 64 + quad * 16 + 8);
        const float4 c0 = *(const float4*)&cosp[srow % S_LEN * 64 + cc * 32 + quad * 8];
        const float4 c1 = *(const float4*)&cosp[srow % S_LEN * 64 + cc * 32 + quad * 8 + 4];
        const float4 s0 = *(const float4*)&sinp[srow % S_LEN * 64 + cc * 32 + quad * 8];
        const float4 s1 = *(const float4*)&sinp[srow % S_LEN * 64 + cc * 32 + quad * 8 + 4];
        const float cA[8] = {c0.x, c0.y, c0.z, c0.w, c1.x, c1.y, c1.z, c1.w};
        const float sA[8] = {s0.x, s0.y, s0.z, s0.w, s1.x, s1.y, s1.z, s1.w};
#pragma unroll
        for (int j = 0; j < 8; ++j) {
          const float p1 = (float)((j < 4) ? r0[2 * j] : r1[2 * (j - 4)]);
          const float p2 = (float)((j < 4) ? r0[2 * j + 1] : r1[2 * (j - 4) + 1]);
          qf[cc][j]     = (_Float16)((p1 * cA[j] - p2 * sA[j]) * QSCALE);
          qf[cc + 2][j] = (_Float16)((p2 * cA[j] + p1 * sA[j]) * QSCALE);
        }
      }
    }

    floatx4 o[8];
#pragma unroll
    for (int d = 0; d < 8; ++d) o[d] = (floatx4){0.f, 0.f, 0.f, 0.f};
    float m_run[4] = {-3e38f, -3e38f, -3e38f, -3e38f};
    float l_run[4] = {0.f, 0.f, 0.f, 0.f};

    for (int kt = 0; kt <= qt; ++kt) {
      const int k0 = kt * 64;
      __syncthreads(); // prior frag reads (incl. previous pass) complete
      {
        const _Float16* g = kgp + (size_t)k0 * QKVSTR;
        _Float16* dst = &Ks[skr][skc];
#pragma unroll
        for (int u = 0; u < 4; ++u)
          *(half8*)(dst + u * 8) = *(const half8*)(g + u * 8);
      }
      {
        const _Float16* g = vgp + k0;
        _Float16* dst = &Vs[svr][svc];
#pragma unroll
        for (int u = 0; u < 4; ++u)
          *(half8*)(dst + u * 8) = *(const half8*)(g + u * 8);
      }
      __syncthreads();

      floatx4 s[4];
#pragma unroll
      for (int i = 0; i < 4; ++i) {
        s[i] = (floatx4){0.f, 0.f, 0.f, 0.f};
#pragma unroll
        for (int c = 0; c < 4; ++c) {
          const half8 kf = *(const half8*)&Ks[i * 16 + l16][quad * 8 + c * 32];
          s[i] = __builtin_amdgcn_mfma_f32_16x16x32_f16(qf[c], kf, s[i], 0, 0, 0);
        }
      }

      if (kt == qt) {
#pragma unroll
        for (int i = 0; i < 4; ++i) {
          const int kpos = k0 + i * 16 + l16;
#pragma unroll
          for (int r = 0; r < 4; ++r)
            if (kpos > q0 + quad * 4 + r) s[i][r] = -3.0e38f;
        }
      }

      float p[4][4];
#pragma unroll
      for (int r = 0; r < 4; ++r) {
        float rm = fmaxf(fmaxf(s[0][r], s[1][r]), fmaxf(s[2][r], s[3][r]));
        rm = fmaxf(rm, __shfl_xor(rm, 1));
        rm = fmaxf(rm, __shfl_xor(rm, 2));
        rm = fmaxf(rm, __shfl_xor(rm, 4));
        rm = fmaxf(rm, __shfl_xor(rm, 8));
        const float mnew = fmaxf(m_run[r], rm);
        const float alpha = exp2f(m_run[r] - mnew);
        m_run[r] = mnew;
        float rs = 0.f;
#pragma unroll
        for (int i = 0; i < 4; ++i) { p[i][r] = exp2f(s[i][r] - mnew); rs += p[i][r]; }
        rs += __shfl_xor(rs, 1);
        rs += __shfl_xor(rs, 2);
        rs += __shfl_xor(rs, 4);
        rs += __shfl_xor(rs, 8);
        l_run[r] = l_run[r] * alpha + rs;
#pragma unroll
        for (int d = 0; d < 8; ++d) o[d][r] *= alpha;
      }

      const int odd = l16 & 1;
      const int cbase = l16 & 14;
#pragma unroll
      for (int i = 0; i < 4; ++i) {
#pragma unroll
        for (int rr = 0; rr < 2; ++rr) {
          const float send = odd ? p[i][rr] : p[i][2 + rr];
          const float recv = __shfl_xor(send, 1);
          const float lo = odd ? recv : p[i][rr];
          const float hi = odd ? p[i][2 + rr] : recv;
          *(half2v*)&Ps[wave][quad * 4 + 2 * odd + rr][i * 16 + cbase] = pack2h(lo, hi);
        }
      }
      const half8 pf0 = *(const half8*)&Ps[wave][l16][quad * 8];
      const half8 pf1 = *(const half8*)&Ps[wave][l16][32 + quad * 8];

#pragma unroll
      for (int d = 0; d < 8; ++d) {
        const half8 vf0 = *(const half8*)&Vs[d * 16 + l16][quad * 8];
        const half8 vf1 = *(const half8*)&Vs[d * 16 + l16][32 + quad * 8];
        o[d] = __builtin_amdgcn_mfma_f32_16x16x32_f16(pf0, vf0, o[d], 0, 0, 0);
        o[d] = __builtin_amdgcn_mfma_f32_16x16x32_f16(pf1, vf1, o[d], 0, 0, 0);
      }
    }

    // ---- epilogue for this pass ----
    float inv[4];
#pragma unroll
    for (int r = 0; r < 4; ++r) inv[r] = 1.0f / l_run[r];
#pragma unroll
    for (int d = 0; d < 8; ++d)
#pragma unroll
      for (int r = 0; r < 4; ++r)
        aout[(size_t)(b * S_LEN + q0 + quad * 4 + r) * DMODEL + h * HD + d * 16 + l16] =
            f2bf(o[d][r] * inv[r]);
  }
}

// ---------------------------------------------------------------------------
extern "C" void kernel_launch(void* const* d_in, const int* in_sizes, int n_in,
                              void* d_out, int out_size, void* d_ws, size_t ws_size,
                              hipStream_t stream) {
  const float* hs   = (const float*)d_in[0];
  const float* cosp = (const float*)d_in[2];
  const float* sinp = (const float*)d_in[3];
  const float* Wq   = (const float*)d_in[4];
  const float* Wk   = (const float*)d_in[5];
  const float* Wv   = (const float*)d_in[6];
  const float* Wo   = (const float*)d_in[7];
  float* out = (float*)d_out;

  // ws layout (58.7 MB):
  //   hsb bf16 [4096][2048] 16.8M (dead after qkv GEMM -> aliased by ao)
  //   Wt  bf16 [3072][2048] 12.6M (fused Wq|Wk|Wv transposed; later Wo)
  //   qkv f16  [4096][3072] 25.2M (q raw | k roped in-place | v)
  //   Vt  f16  [2][4][128][2048] 4.2M
  char* w = (char*)d_ws;
  short*    hsb = (short*)w;
  short*    Wt  = (short*)(w + 16777216);
  _Float16* qkv = (_Float16*)(w + 29360128);
  _Float16* Vt  = (_Float16*)(w + 54525952);
  short*    ao  = hsb; // safe alias: hsb dead after the fused qkv GEMM

  _Float16* qh = qkv;
  _Float16* kh = qkv + 2048;
  _Float16* vh = qkv + 2560;

  dim3 blk(256);
  cast_bf16<<<MROWS * DMODEL / (8 * 256), blk, 0, stream>>>(hs, hsb);
  tcast<<<dim3(DMODEL / 64, DMODEL / 64), blk, 0, stream>>>(Wq, Wt, DMODEL);
  tcast<<<dim3(KVD / 64, DMODEL / 64), blk, 0, stream>>>(Wk, Wt + (size_t)2048 * DMODEL, KVD);
  tcast<<<dim3(KVD / 64, DMODEL / 64), blk, 0, stream>>>(Wv, Wt + (size_t)2560 * DMODEL, KVD);
  gemm_glds<true><<<dim3(QKVSTR / 128, MROWS / 128), blk, 0, stream>>>(hsb, Wt, qkv, MROWS, QKVSTR, DMODEL);
  rope_k<<<MROWS / 4, blk, 0, stream>>>(kh, cosp, sinp);
  vtprep<<<dim3(MROWS / 64, KVD / 64), blk, 0, stream>>>(vh, Vt);
  attn_mfma<<<dim3(NQT / 2, NH, BATCH), blk, 0, stream>>>(qh, kh, Vt, cosp, sinp, ao);
  tcast<<<dim3(DMODEL / 64, DMODEL / 64), blk, 0, stream>>>(Wo, Wt, DMODEL);
  gemm_glds<false><<<dim3(DMODEL / 128, MROWS / 128), blk, 0, stream>>>(ao, Wt, out, MROWS, DMODEL, DMODEL);
}